// Round 10
// baseline (266.764 us; speedup 1.0000x reference)
//
#include <hip/hip_runtime.h>
#include <hip/hip_bf16.h>

// MHA: B=1, S=4096, D=768, H=12, DK=64.
// Round 20: R19 post-mortem — oproj-combine fusion cost +12 us (staging-path
//   fusion hurts; twice-confirmed). REVERT to R16 pipeline (separate combine,
//   pure-f16 GEMM staging). NEW: retry R17's occupancy structure WITHOUT the
//   spill: flash KVBLK=32, nseg=4 (runtime, ws-checked), launch_bounds
//   (256,4) so VGPR cap is 128 (kernel needs ~64; R17's (256,6) capped at 40
//   -> 425 MB scratch spill). 6 blocks/CU co-resident (108 KiB LDS), 24
//   waves/CU vs R16's 12. Per-wave MFMA:ds ratios preserved (uniform halving,
//   not R15's width cut). R17 already proved this path numerically correct.
// Spill check on counters: expect VGPR~64, WRITE~28 MB. If VGPR=40: revert.

constexpr int S_LEN = 4096;
constexpr int D_MODEL = 768;
constexpr int N_HEADS = 12;
constexpr int D_HEAD = 64;

// Q pre-scale: (1/sqrt(64)) * log2(e)  -> scores in exp2 domain
#define QSCALE 0.180336880111120f

typedef _Float16 f16;
typedef __attribute__((ext_vector_type(8))) _Float16 f16x8;
typedef __attribute__((ext_vector_type(4))) _Float16 f16x4;
typedef __attribute__((ext_vector_type(4))) float f32x4;

// ---------------------------------------------------------------------------
// Merged prep: blocks [0, 4608) = f32->f16 convert of q,k,v (8 elem/thread);
//              blocks [4608, 5184) = W transpose+convert (144 blocks per W).
// ---------------------------------------------------------------------------
__global__ __launch_bounds__(256) void prep_kernel(
    const float* __restrict__ q, const float* __restrict__ k,
    const float* __restrict__ v, f16* __restrict__ qh,
    f16* __restrict__ kh, f16* __restrict__ vh,
    const float* __restrict__ W0, const float* __restrict__ W1,
    const float* __restrict__ W2, const float* __restrict__ W3,
    f16* __restrict__ WtBase)
{
    __shared__ float T[64][65];
    int bid = blockIdx.x;
    const int t = threadIdx.x;
    if (bid < 4608) {
        int g = bid / 1536, r = bid % 1536;
        const float* x = (g == 0) ? q : (g == 1) ? k : v;
        f16* y = (g == 0) ? qh : (g == 1) ? kh : vh;
        int i = (r * 256 + t) * 8;
        float4 a = *(const float4*)&x[i];
        float4 b = *(const float4*)&x[i + 4];
        f16x8 h = { (f16)a.x, (f16)a.y, (f16)a.z, (f16)a.w,
                    (f16)b.x, (f16)b.y, (f16)b.z, (f16)b.w };
        *(f16x8*)&y[i] = h;
        return;
    }
    bid -= 4608;
    int g = bid / 144, r = bid % 144;
    const float* W = (g == 0) ? W0 : (g == 1) ? W1 : (g == 2) ? W2 : W3;
    f16* Wt = WtBase + (size_t)g * D_MODEL * D_MODEL;
    const int r0 = (r / 12) * 64;
    const int c0 = (r % 12) * 64;
    #pragma unroll
    for (int i = 0; i < 16; ++i) {
        int e = t + 256 * i; int rr = e >> 6, cc = e & 63;
        T[rr][cc] = W[(size_t)(r0 + rr) * D_MODEL + c0 + cc];
    }
    __syncthreads();
    #pragma unroll
    for (int i = 0; i < 16; ++i) {
        int e = t + 256 * i; int rr = e >> 6, cc = e & 63;
        Wt[(size_t)(c0 + rr) * D_MODEL + r0 + cc] = (f16)T[cc][rr];
    }
}

// ---------------------------------------------------------------------------
// 128x128 GEMM core with register-prefetch pipeline (R10-proven, unchanged).
// Both operands k-contiguous (B^T form), BK=64. 4 waves 2x2; LDS stride 72.
// Staging is PURE f16 copies — R18/R19 proved fusing work here regresses.
// ---------------------------------------------------------------------------
#define GSTR 72

__device__ __forceinline__ void gemm128_core(
    const f16* __restrict__ A, const f16* __restrict__ B,
    f16* As, f16* Bs, int K, int row0, int col0, int t, f32x4 acc[4][4])
{
    const int w = t >> 6, l = t & 63, quad = l >> 4, l15 = l & 15;
    const int wm = (w & 1) * 64, wn = (w >> 1) * 64;

    f16x8 pa[4], pb[4];
    #pragma unroll
    for (int i = 0; i < 4; ++i) {
        int idx = i * 256 + t;
        int r = idx >> 3, c = (idx & 7) * 8;
        pa[i] = *(const f16x8*)&A[(size_t)(row0 + r) * K + c];
        pb[i] = *(const f16x8*)&B[(size_t)(col0 + r) * K + c];
    }

    for (int k0 = 0; k0 < K; k0 += 64) {
        __syncthreads();
        #pragma unroll
        for (int i = 0; i < 4; ++i) {
            int idx = i * 256 + t;
            int r = idx >> 3, c = (idx & 7) * 8;
            *(f16x8*)&As[r * GSTR + c] = pa[i];
            *(f16x8*)&Bs[r * GSTR + c] = pb[i];
        }
        __syncthreads();

        int kn = k0 + 64;
        if (kn < K) {
            #pragma unroll
            for (int i = 0; i < 4; ++i) {
                int idx = i * 256 + t;
                int r = idx >> 3, c = (idx & 7) * 8;
                pa[i] = *(const f16x8*)&A[(size_t)(row0 + r) * K + kn + c];
                pb[i] = *(const f16x8*)&B[(size_t)(col0 + r) * K + kn + c];
            }
        }

        #pragma unroll
        for (int kc = 0; kc < 2; ++kc) {
            f16x8 af[4], bf[4];
            #pragma unroll
            for (int mt = 0; mt < 4; ++mt)
                af[mt] = *(f16x8*)&As[(wm + mt * 16 + l15) * GSTR + kc * 32 + quad * 8];
            #pragma unroll
            for (int nt = 0; nt < 4; ++nt)
                bf[nt] = *(f16x8*)&Bs[(wn + nt * 16 + l15) * GSTR + kc * 32 + quad * 8];
            #pragma unroll
            for (int mt = 0; mt < 4; ++mt)
                #pragma unroll
                for (int nt = 0; nt < 4; ++nt)
                    acc[mt][nt] = __builtin_amdgcn_mfma_f32_16x16x32_f16(
                        af[mt], bf[nt], acc[mt][nt], 0, 0, 0);
        }
    }
}

// ---------------------------------------------------------------------------
// Batched QKV projections (f16 inputs), 128x128 tiles, 192 blocks per GEMM:
//  g0: Qp=(qh@Wtq^T+bq)*QSCALE [SxD]; g1: Kp [SxD]; g2: Vpt=Wtv@vh^T+bv [DxS].
// ---------------------------------------------------------------------------
__global__ __launch_bounds__(256) void qkv_gemm_kernel(
    const f16* __restrict__ qh, const f16* __restrict__ kh,
    const f16* __restrict__ vh, const f16* __restrict__ WtBase,
    const float* __restrict__ bq, const float* __restrict__ bk,
    const float* __restrict__ bv,
    f16* __restrict__ Qp, f16* __restrict__ Kp, f16* __restrict__ Vpt)
{
    __shared__ f16 As[128 * GSTR];
    __shared__ f16 Bs[128 * GSTR];
    const size_t DD = (size_t)D_MODEL * D_MODEL;
    int bid = blockIdx.x;
    int g = bid / 192, r = bid % 192;

    const f16 *A, *B; const float* bias; f16* Y;
    int N; bool biasRow; float scale;
    int row0, col0;
    if (g == 0) {
        A = qh; B = WtBase; bias = bq; Y = Qp;
        N = D_MODEL; biasRow = false; scale = QSCALE;
        row0 = (r / 6) * 128; col0 = (r % 6) * 128;
    } else if (g == 1) {
        A = kh; B = WtBase + DD; bias = bk; Y = Kp;
        N = D_MODEL; biasRow = false; scale = 1.0f;
        row0 = (r / 6) * 128; col0 = (r % 6) * 128;
    } else {
        A = WtBase + 2 * DD; B = vh; bias = bv; Y = Vpt;
        N = S_LEN; biasRow = true; scale = 1.0f;
        row0 = (r / 32) * 128; col0 = (r % 32) * 128;
    }

    f32x4 acc[4][4];
    #pragma unroll
    for (int i = 0; i < 4; ++i)
        #pragma unroll
        for (int j = 0; j < 4; ++j) acc[i][j] = (f32x4){0.f, 0.f, 0.f, 0.f};

    const int t = threadIdx.x;
    gemm128_core(A, B, As, Bs, D_MODEL, row0, col0, t, acc);

    const int w = t >> 6, l = t & 63, quad = l >> 4, l15 = l & 15;
    const int wm = (w & 1) * 64, wn = (w >> 1) * 64;
    #pragma unroll
    for (int mt = 0; mt < 4; ++mt) {
        #pragma unroll
        for (int nt = 0; nt < 4; ++nt) {
            int col = col0 + wn + nt * 16 + l15;
            #pragma unroll
            for (int reg = 0; reg < 4; ++reg) {
                int row = row0 + wm + mt * 16 + quad * 4 + reg;
                float b = biasRow ? bias[row] : bias[col];
                Y[(size_t)row * N + col] = (f16)((acc[mt][nt][reg] + b) * scale);
            }
        }
    }
}

// ---------------------------------------------------------------------------
// Flash attention, transposed-score form, P in registers, qt=2.
// R20: KVBLK=32, runtime nseg (grid.z), 6 blocks/CU; launch_bounds (256,4)
// so VGPR cap = 128 (no spill — R17's (256,6) capped at 40 and spilled).
// K rows sigma-permuted at LDS-store so PV runs full-rate 16x16x32 MFMA.
// Ping-pong K/V LDS: one barrier per k-iter; prefetch issued post-barrier.
// ---------------------------------------------------------------------------
#define LSTRK 72   // K tile stride (f16): 32 rows x 64 dk (+8 pad)
#define VSTR  36   // V tile stride (f16): 64 dv rows x 32 kv (+4 pad)

__global__ __launch_bounds__(256, 4) void flash_attn_part_kernel(
    const f16* __restrict__ Q, const f16* __restrict__ K,
    const f16* __restrict__ Vg, f16* __restrict__ Opart,
    float* __restrict__ lsum, int seg_len)
{
    __shared__ f16 Ks[2][32 * LSTRK];
    __shared__ f16 Vt[2][64 * VSTR];

    const int t    = threadIdx.x;
    const int w    = t >> 6;
    const int l    = t & 63;
    const int quad = l >> 4;
    const int l15  = l & 15;
    const int h    = blockIdx.y;
    const int q0   = blockIdx.x * 128;
    const int seg  = blockIdx.z;
    const int c0   = h * D_HEAD;
    const size_t SD = (size_t)S_LEN * D_MODEL;
    const int NIT  = seg_len >> 5;          // iters of 32 kv rows

    // staging coords (per thread, fixed)
    const int sr  = t >> 3;           // K row 0..31
    const int sc  = (t & 7) * 8;      // K col chunk (dk)
    // sigma: kv = q*8 + h2*4 + r -> row = h2*16 + q*4 + r   (within 32)
    const int srk = ((sr & 4) << 2) | ((sr & 24) >> 1) | (sr & 3);
    const int svr = t >> 2;           // V dv row 0..63
    const int svc = (t & 3) * 8;      // V kv chunk

    // Q fragments (B-operand for S^T), direct from global, resident all loop
    f16x8 qa[2][2];
    #pragma unroll
    for (int qt = 0; qt < 2; ++qt) {
        const f16* qrow = Q + (size_t)(q0 + w * 32 + qt * 16 + l15) * D_MODEL + c0;
        qa[qt][0] = *(const f16x8*)&qrow[quad * 8];
        qa[qt][1] = *(const f16x8*)&qrow[32 + quad * 8];
    }

    f32x4 ctx[2][4];          // [q-tile][dv-tile], C rows = dv, cols = q
    float lAcc[2] = {0.f, 0.f};
    #pragma unroll
    for (int qt = 0; qt < 2; ++qt)
        #pragma unroll
        for (int i = 0; i < 4; ++i) ctx[qt][i] = (f32x4){0.f, 0.f, 0.f, 0.f};

    const int kt0 = seg * seg_len;

    // ---- prologue: tile 0 -> buf 0; prefetch tile 1 after the barrier ----
    f16x8 kreg, vreg;
    kreg = *(const f16x8*)&K[(size_t)(kt0 + sr) * D_MODEL + c0 + sc];
    vreg = *(const f16x8*)&Vg[(size_t)(c0 + svr) * S_LEN + kt0 + svc];
    *(f16x8*)&Ks[0][srk * LSTRK + sc] = kreg;
    *(f16x8*)&Vt[0][svr * VSTR + svc] = vreg;
    __syncthreads();
    kreg = *(const f16x8*)&K[(size_t)(kt0 + 32 + sr) * D_MODEL + c0 + sc];
    vreg = *(const f16x8*)&Vg[(size_t)(c0 + svr) * S_LEN + kt0 + 32 + svc];

    for (int it = 0; it < NIT; ++it) {
        const int buf = it & 1;
        const f16* ks = Ks[buf];
        const f16* vt = Vt[buf];

        // ---- scores: 2 half-tiles; LDS rows linear (store applied sigma).
        //      Lane (quad,l15) of tile half yields P[kv=quad*8+half*4+reg][q].
        f16x8 pf[2];          // [qt] -> K=32 B-operand fragment
        #pragma unroll
        for (int half = 0; half < 2; ++half) {
            const f16* kr = &ks[(half * 16 + l15) * LSTRK];
            f16x8 kb0 = *(const f16x8*)&kr[quad * 8];
            f16x8 kb1 = *(const f16x8*)&kr[32 + quad * 8];
            #pragma unroll
            for (int qt = 0; qt < 2; ++qt) {
                f32x4 z = (f32x4){0.f, 0.f, 0.f, 0.f};
                z = __builtin_amdgcn_mfma_f32_16x16x32_f16(kb0, qa[qt][0], z, 0, 0, 0);
                z = __builtin_amdgcn_mfma_f32_16x16x32_f16(kb1, qa[qt][1], z, 0, 0, 0);
                float p0 = __builtin_amdgcn_exp2f(z[0]);
                float p1 = __builtin_amdgcn_exp2f(z[1]);
                float p2 = __builtin_amdgcn_exp2f(z[2]);
                float p3 = __builtin_amdgcn_exp2f(z[3]);
                lAcc[qt] += (p0 + p1) + (p2 + p3);
                pf[qt][half * 4 + 0] = (f16)p0;
                pf[qt][half * 4 + 1] = (f16)p1;
                pf[qt][half * 4 + 2] = (f16)p2;
                pf[qt][half * 4 + 3] = (f16)p3;
            }
        }

        // ---- PV at K=32: A = V^T rows dv (lane holds kv = quad*8+j),
        //      B = pf (same kv ordering). 8 full-rate MFMA per wave-iter.
        #pragma unroll
        for (int mt = 0; mt < 4; ++mt) {
            f16x8 va = *(const f16x8*)&vt[(mt * 16 + l15) * VSTR + quad * 8];
            #pragma unroll
            for (int qt = 0; qt < 2; ++qt)
                ctx[qt][mt] = __builtin_amdgcn_mfma_f32_16x16x32_f16(
                    va, pf[qt], ctx[qt][mt], 0, 0, 0);
        }

        // ---- write tile it+1 into the other buffer ----
        if (it + 1 < NIT) {
            *(f16x8*)&Ks[1 - buf][srk * LSTRK + sc] = kreg;
            *(f16x8*)&Vt[1 - buf][svr * VSTR + svc] = vreg;
        }
        __syncthreads();   // the ONLY barrier per iter

        // ---- prefetch tile it+2 (stays in flight through next compute) ----
        if (it + 2 < NIT) {
            int ktn = kt0 + (it + 2) * 32;
            kreg = *(const f16x8*)&K[(size_t)(ktn + sr) * D_MODEL + c0 + sc];
            vreg = *(const f16x8*)&Vg[(size_t)(c0 + svr) * S_LEN + ktn + svc];
        }
    }

    // ---- epilogue: ctx^T rows = dv (4 contiguous per reg-block) ----
    #pragma unroll
    for (int qt = 0; qt < 2; ++qt) {
        int qrow = q0 + w * 32 + qt * 16 + l15;
        #pragma unroll
        for (int mt = 0; mt < 4; ++mt) {
            f16x4 ov = { (f16)ctx[qt][mt][0], (f16)ctx[qt][mt][1],
                         (f16)ctx[qt][mt][2], (f16)ctx[qt][mt][3] };
            *(f16x4*)&Opart[(size_t)seg * SD + (size_t)qrow * D_MODEL
                            + c0 + mt * 16 + quad * 4] = ov;
        }
        float s = lAcc[qt];
        s += __shfl_xor(s, 16);
        s += __shfl_xor(s, 32);
        if (quad == 0)
            lsum[((size_t)seg * N_HEADS + h) * S_LEN + qrow] = s;
    }
}

// ---------------------------------------------------------------------------
// Combine nseg segments in-place: Opart[0] = (sum_s O_s) / (sum_s l_s).
// 1536 blocks. Separate kernel — fusing into oproj staging regressed (R19).
// ---------------------------------------------------------------------------
__global__ __launch_bounds__(256) void combine_kernel(
    f16* Opart, const float* __restrict__ lsum, int nseg)
{
    const size_t SD = (size_t)S_LEN * D_MODEL;
    int tid = blockIdx.x * 256 + threadIdx.x;
    int idx = tid * 8;
    int row = idx / D_MODEL;
    int c   = idx % D_MODEL;
    int hh  = c >> 6;
    float lt = 0.f;
    for (int s = 0; s < nseg; ++s)
        lt += lsum[((size_t)s * N_HEADS + hh) * S_LEN + row];
    float inv = 1.0f / lt;
    float o[8] = {0.f, 0.f, 0.f, 0.f, 0.f, 0.f, 0.f, 0.f};
    for (int s = 0; s < nseg; ++s) {
        f16x8 os = *(const f16x8*)&Opart[(size_t)s * SD + (size_t)row * D_MODEL + c];
        #pragma unroll
        for (int j = 0; j < 8; ++j) o[j] += (float)os[j];
    }
    f16x8 r;
    #pragma unroll
    for (int j = 0; j < 8; ++j)
        r[j] = (f16)(o[j] * inv);
    *(f16x8*)&Opart[(size_t)row * D_MODEL + c] = r;
}

// ---------------------------------------------------------------------------
// O-projection: out_f32 = Ctx @ Wto^T + bo.  128x128 tiles, 192 blocks.
// ---------------------------------------------------------------------------
__global__ __launch_bounds__(256) void oproj_kernel(
    const f16* __restrict__ Ctx, const f16* __restrict__ Wto,
    const float* __restrict__ bo, float* __restrict__ out)
{
    __shared__ f16 As[128 * GSTR];
    __shared__ f16 Bs[128 * GSTR];
    int bid = blockIdx.x;
    int row0 = (bid / 6) * 128, col0 = (bid % 6) * 128;

    f32x4 acc[4][4];
    #pragma unroll
    for (int i = 0; i < 4; ++i)
        #pragma unroll
        for (int j = 0; j < 4; ++j) acc[i][j] = (f32x4){0.f, 0.f, 0.f, 0.f};

    const int t = threadIdx.x;
    gemm128_core(Ctx, Wto, As, Bs, D_MODEL, row0, col0, t, acc);

    const int w = t >> 6, l = t & 63, quad = l >> 4, l15 = l & 15;
    const int wm = (w & 1) * 64, wn = (w >> 1) * 64;
    #pragma unroll
    for (int mt = 0; mt < 4; ++mt) {
        #pragma unroll
        for (int nt = 0; nt < 4; ++nt) {
            int col = col0 + wn + nt * 16 + l15;
            float b = bo[col];
            #pragma unroll
            for (int reg = 0; reg < 4; ++reg) {
                int row = row0 + wm + mt * 16 + quad * 4 + reg;
                out[(size_t)row * D_MODEL + col] = acc[mt][nt][reg] + b;
            }
        }
    }
}

// ---------------------------------------------------------------------------
extern "C" void kernel_launch(void* const* d_in, const int* in_sizes, int n_in,
                              void* d_out, int out_size, void* d_ws, size_t ws_size,
                              hipStream_t stream)
{
    const float* q  = (const float*)d_in[0];
    const float* k  = (const float*)d_in[1];
    const float* v  = (const float*)d_in[2];
    const float* Wq = (const float*)d_in[3];
    const float* bq = (const float*)d_in[4];
    const float* Wk = (const float*)d_in[5];
    const float* bk = (const float*)d_in[6];
    const float* Wv = (const float*)d_in[7];
    const float* bv = (const float*)d_in[8];
    const float* Wo = (const float*)d_in[9];
    const float* bo = (const float*)d_in[10];
    float* out = (float*)d_out;

    const size_t SD = (size_t)S_LEN * D_MODEL;
    const size_t DD = (size_t)D_MODEL * D_MODEL;
    f16* base   = (f16*)d_ws;
    f16* WtBase = base;                  // Wtq|Wtk|Wtv|Wto (4*DD)
    f16* Wto    = WtBase + 3 * DD;
    f16* Qp     = base + 4 * DD;
    f16* Kp     = Qp + SD;
    f16* Vpt    = Kp + SD;               // [D][S]
    f16* qh     = Vpt + SD;              // 3SD region, reused after qkv_gemm
    f16* kh     = qh + SD;
    f16* vh     = kh + SD;
    f16* Opart  = qh;                    // nseg*SD (aliases qh,kh,vh[,+1SD])

    // choose nseg=4 if workspace allows (4DD + 3SD + 4SD f16 + lsum f32)
    const size_t need4 = (4 * DD + 7 * SD) * sizeof(f16)
                       + 4 * (size_t)N_HEADS * S_LEN * sizeof(float);
    const int nseg = (ws_size >= need4) ? 4 : 2;
    const int seg_len = S_LEN / nseg;
    float* lsum = (float*)(base + 4 * DD + (3 + (size_t)nseg) * SD);

    prep_kernel<<<3 * 1536 + 4 * 144, 256, 0, stream>>>(
        q, k, v, qh, kh, vh, Wq, Wk, Wv, Wo, WtBase);

    qkv_gemm_kernel<<<3 * 192, 256, 0, stream>>>(
        qh, kh, vh, WtBase, bq, bk, bv, Qp, Kp, Vpt);

    dim3 gAttn(S_LEN / 128, N_HEADS, nseg);   // (32, 12, nseg)
    flash_attn_part_kernel<<<gAttn, 256, 0, stream>>>(
        Qp, Kp, Vpt, Opart, lsum, seg_len);

    combine_kernel<<<1536, 256, 0, stream>>>(Opart, lsum, nseg);

    oproj_kernel<<<192, 256, 0, stream>>>(Opart, Wto, bo, out);
}

// Round 11
// 224.254 us; speedup vs baseline: 1.1896x; 1.1896x over previous
//
#include <hip/hip_runtime.h>
#include <hip/hip_bf16.h>

// MHA: B=1, S=4096, D=768, H=12, DK=64.
// Round 21: R20 post-mortem — KVBLK=32 flash is latency-bound even without
//   spill (126 us, MfmaUtil 16.5): compute phase too short to hide prefetch
//   latency + V coalescing worsened. Occupancy route closed (3 failures:
//   R15 width, R17 spill, R20 depth). Flash REVERTED to exact R16 (66 us).
// NEW (one variable): gemm128_core (qkv+oproj) converted from 2-barrier to
//   flash-style ONE-barrier ping-pong LDS with post-barrier 2-tile-distance
//   prefetch. LDS 36->72 KiB (2 blk/CU; grid 2.25/0.75 per CU is the binding
//   limit anyway). The old core stalled every K-iter: prefetch had only the
//   ~150-350 cyc compute tail to cover ~900 cyc HBM latency. Now loads stay
//   in flight across a full compute+write phase.
// Staging stays pure f16 (R18) and combine stays separate (R19).

constexpr int S_LEN = 4096;
constexpr int D_MODEL = 768;
constexpr int N_HEADS = 12;
constexpr int D_HEAD = 64;
constexpr int SEG = 2;
constexpr int SEG_LEN = S_LEN / SEG;   // 2048
constexpr int NITER = SEG_LEN / 64;    // 32

// Q pre-scale: (1/sqrt(64)) * log2(e)  -> scores in exp2 domain
#define QSCALE 0.180336880111120f

typedef _Float16 f16;
typedef __attribute__((ext_vector_type(8))) _Float16 f16x8;
typedef __attribute__((ext_vector_type(4))) _Float16 f16x4;
typedef __attribute__((ext_vector_type(4))) float f32x4;

// ---------------------------------------------------------------------------
// Merged prep: blocks [0, 4608) = f32->f16 convert of q,k,v (8 elem/thread);
//              blocks [4608, 5184) = W transpose+convert (144 blocks per W).
// ---------------------------------------------------------------------------
__global__ __launch_bounds__(256) void prep_kernel(
    const float* __restrict__ q, const float* __restrict__ k,
    const float* __restrict__ v, f16* __restrict__ qh,
    f16* __restrict__ kh, f16* __restrict__ vh,
    const float* __restrict__ W0, const float* __restrict__ W1,
    const float* __restrict__ W2, const float* __restrict__ W3,
    f16* __restrict__ WtBase)
{
    __shared__ float T[64][65];
    int bid = blockIdx.x;
    const int t = threadIdx.x;
    if (bid < 4608) {
        int g = bid / 1536, r = bid % 1536;
        const float* x = (g == 0) ? q : (g == 1) ? k : v;
        f16* y = (g == 0) ? qh : (g == 1) ? kh : vh;
        int i = (r * 256 + t) * 8;
        float4 a = *(const float4*)&x[i];
        float4 b = *(const float4*)&x[i + 4];
        f16x8 h = { (f16)a.x, (f16)a.y, (f16)a.z, (f16)a.w,
                    (f16)b.x, (f16)b.y, (f16)b.z, (f16)b.w };
        *(f16x8*)&y[i] = h;
        return;
    }
    bid -= 4608;
    int g = bid / 144, r = bid % 144;
    const float* W = (g == 0) ? W0 : (g == 1) ? W1 : (g == 2) ? W2 : W3;
    f16* Wt = WtBase + (size_t)g * D_MODEL * D_MODEL;
    const int r0 = (r / 12) * 64;
    const int c0 = (r % 12) * 64;
    #pragma unroll
    for (int i = 0; i < 16; ++i) {
        int e = t + 256 * i; int rr = e >> 6, cc = e & 63;
        T[rr][cc] = W[(size_t)(r0 + rr) * D_MODEL + c0 + cc];
    }
    __syncthreads();
    #pragma unroll
    for (int i = 0; i < 16; ++i) {
        int e = t + 256 * i; int rr = e >> 6, cc = e & 63;
        Wt[(size_t)(c0 + rr) * D_MODEL + r0 + cc] = (f16)T[cc][rr];
    }
}

// ---------------------------------------------------------------------------
// 128x128 GEMM core — R21: ONE-barrier ping-pong LDS (flash-proven pattern).
// Both operands k-contiguous (B^T form), BK=64. 4 waves 2x2; LDS stride 72.
// As/Bs each hold TWO 128x72 buffers. Prefetch distance 2 tiles.
// Staging is PURE f16 copies — R18/R19 proved fusing work here regresses.
// ---------------------------------------------------------------------------
#define GSTR 72
#define GBOFF (128 * GSTR)

__device__ __forceinline__ void gemm128_core(
    const f16* __restrict__ A, const f16* __restrict__ B,
    f16* As, f16* Bs, int K, int row0, int col0, int t, f32x4 acc[4][4])
{
    const int w = t >> 6, l = t & 63, quad = l >> 4, l15 = l & 15;
    const int wm = (w & 1) * 64, wn = (w >> 1) * 64;
    const int NI = K >> 6;

    f16x8 pa[4], pb[4];

    auto loadT = [&](int kk) {
        #pragma unroll
        for (int i = 0; i < 4; ++i) {
            int idx = i * 256 + t;
            int r = idx >> 3, c = (idx & 7) * 8;
            pa[i] = *(const f16x8*)&A[(size_t)(row0 + r) * K + kk + c];
            pb[i] = *(const f16x8*)&B[(size_t)(col0 + r) * K + kk + c];
        }
    };
    auto writeT = [&](int buf) {
        #pragma unroll
        for (int i = 0; i < 4; ++i) {
            int idx = i * 256 + t;
            int r = idx >> 3, c = (idx & 7) * 8;
            *(f16x8*)&As[buf * GBOFF + r * GSTR + c] = pa[i];
            *(f16x8*)&Bs[buf * GBOFF + r * GSTR + c] = pb[i];
        }
    };

    // prologue: tile 0 -> buf 0; barrier; issue tile 1 loads (stay in flight
    // through tile 0's whole compute phase)
    loadT(0);
    writeT(0);
    __syncthreads();
    if (NI > 1) loadT(64);

    for (int it = 0; it < NI; ++it) {
        const int buf = it & 1;
        const f16* as = As + buf * GBOFF;
        const f16* bs = Bs + buf * GBOFF;

        #pragma unroll
        for (int kc = 0; kc < 2; ++kc) {
            f16x8 af[4], bf[4];
            #pragma unroll
            for (int mt = 0; mt < 4; ++mt)
                af[mt] = *(const f16x8*)&as[(wm + mt * 16 + l15) * GSTR + kc * 32 + quad * 8];
            #pragma unroll
            for (int nt = 0; nt < 4; ++nt)
                bf[nt] = *(const f16x8*)&bs[(wn + nt * 16 + l15) * GSTR + kc * 32 + quad * 8];
            #pragma unroll
            for (int mt = 0; mt < 4; ++mt)
                #pragma unroll
                for (int nt = 0; nt < 4; ++nt)
                    acc[mt][nt] = __builtin_amdgcn_mfma_f32_16x16x32_f16(
                        af[mt], bf[nt], acc[mt][nt], 0, 0, 0);
        }

        // write tile it+1 into the other buffer (vmcnt wait lands here, a
        // full compute phase after the loads were issued)
        if (it + 1 < NI) writeT(1 - buf);
        __syncthreads();   // the ONLY barrier per K-step

        // prefetch tile it+2 (in flight through the next compute phase)
        if (it + 2 < NI) loadT((it + 2) * 64);
    }
}

// ---------------------------------------------------------------------------
// Batched QKV projections (f16 inputs), 128x128 tiles, 192 blocks per GEMM:
//  g0: Qp=(qh@Wtq^T+bq)*QSCALE [SxD]; g1: Kp [SxD]; g2: Vpt=Wtv@vh^T+bv [DxS].
// ---------------------------------------------------------------------------
__global__ __launch_bounds__(256) void qkv_gemm_kernel(
    const f16* __restrict__ qh, const f16* __restrict__ kh,
    const f16* __restrict__ vh, const f16* __restrict__ WtBase,
    const float* __restrict__ bq, const float* __restrict__ bk,
    const float* __restrict__ bv,
    f16* __restrict__ Qp, f16* __restrict__ Kp, f16* __restrict__ Vpt)
{
    __shared__ f16 As[2 * GBOFF];
    __shared__ f16 Bs[2 * GBOFF];
    const size_t DD = (size_t)D_MODEL * D_MODEL;
    int bid = blockIdx.x;
    int g = bid / 192, r = bid % 192;

    const f16 *A, *B; const float* bias; f16* Y;
    int N; bool biasRow; float scale;
    int row0, col0;
    if (g == 0) {
        A = qh; B = WtBase; bias = bq; Y = Qp;
        N = D_MODEL; biasRow = false; scale = QSCALE;
        row0 = (r / 6) * 128; col0 = (r % 6) * 128;
    } else if (g == 1) {
        A = kh; B = WtBase + DD; bias = bk; Y = Kp;
        N = D_MODEL; biasRow = false; scale = 1.0f;
        row0 = (r / 6) * 128; col0 = (r % 6) * 128;
    } else {
        A = WtBase + 2 * DD; B = vh; bias = bv; Y = Vpt;
        N = S_LEN; biasRow = true; scale = 1.0f;
        row0 = (r / 32) * 128; col0 = (r % 32) * 128;
    }

    f32x4 acc[4][4];
    #pragma unroll
    for (int i = 0; i < 4; ++i)
        #pragma unroll
        for (int j = 0; j < 4; ++j) acc[i][j] = (f32x4){0.f, 0.f, 0.f, 0.f};

    const int t = threadIdx.x;
    gemm128_core(A, B, As, Bs, D_MODEL, row0, col0, t, acc);

    const int w = t >> 6, l = t & 63, quad = l >> 4, l15 = l & 15;
    const int wm = (w & 1) * 64, wn = (w >> 1) * 64;
    #pragma unroll
    for (int mt = 0; mt < 4; ++mt) {
        #pragma unroll
        for (int nt = 0; nt < 4; ++nt) {
            int col = col0 + wn + nt * 16 + l15;
            #pragma unroll
            for (int reg = 0; reg < 4; ++reg) {
                int row = row0 + wm + mt * 16 + quad * 4 + reg;
                float b = biasRow ? bias[row] : bias[col];
                Y[(size_t)row * N + col] = (f16)((acc[mt][nt][reg] + b) * scale);
            }
        }
    }
}

// ---------------------------------------------------------------------------
// Flash attention — EXACT R16 structure (66 us proven): 256 thr, 4 waves,
// qt=2, SEG=2, KVBLK=64, ping-pong K/V LDS, one barrier per k-iter,
// K rows sigma-permuted at LDS-store so PV runs full-rate 16x16x32 MFMA.
// ---------------------------------------------------------------------------
#define LSTR 72

__global__ __launch_bounds__(256, 4) void flash_attn_part_kernel(
    const f16* __restrict__ Q, const f16* __restrict__ K,
    const f16* __restrict__ Vg, f16* __restrict__ Opart,
    float* __restrict__ lsum)
{
    __shared__ f16 Ks[2][64 * LSTR];
    __shared__ f16 Vt[2][64 * LSTR];

    const int t    = threadIdx.x;
    const int w    = t >> 6;
    const int l    = t & 63;
    const int quad = l >> 4;
    const int l15  = l & 15;
    const int h    = blockIdx.y;
    const int q0   = blockIdx.x * 128;
    const int seg  = blockIdx.z;
    const int c0   = h * D_HEAD;
    const size_t SD = (size_t)S_LEN * D_MODEL;

    const int sr = t >> 3;            // row 0..31  (r = i*32+sr)
    const int sc = (t & 7) * 8;       // f16 col chunk
    // sigma: kv = q*8 + h2*4 + rr -> row = h2*16 + q*4 + rr
    const int srk = ((sr & 4) << 2) | ((sr & 24) >> 1) | (sr & 3);

    f16x8 qa[2][2];
    #pragma unroll
    for (int qt = 0; qt < 2; ++qt) {
        const f16* qrow = Q + (size_t)(q0 + w * 32 + qt * 16 + l15) * D_MODEL + c0;
        qa[qt][0] = *(const f16x8*)&qrow[quad * 8];
        qa[qt][1] = *(const f16x8*)&qrow[32 + quad * 8];
    }

    f32x4 ctx[2][4];
    float lAcc[2] = {0.f, 0.f};
    #pragma unroll
    for (int qt = 0; qt < 2; ++qt)
        #pragma unroll
        for (int i = 0; i < 4; ++i) ctx[qt][i] = (f32x4){0.f, 0.f, 0.f, 0.f};

    const int kt0 = seg * SEG_LEN;

    f16x8 kreg[2], vreg[2];
    #pragma unroll
    for (int i = 0; i < 2; ++i) {
        int r = i * 32 + sr;
        kreg[i] = *(const f16x8*)&K[(size_t)(kt0 + r) * D_MODEL + c0 + sc];
        vreg[i] = *(const f16x8*)&Vg[(size_t)(c0 + r) * S_LEN + kt0 + sc];
    }
    #pragma unroll
    for (int i = 0; i < 2; ++i) {
        int r = i * 32 + sr;
        *(f16x8*)&Ks[0][(i * 32 + srk) * LSTR + sc] = kreg[i];
        *(f16x8*)&Vt[0][r * LSTR + sc] = vreg[i];
    }
    __syncthreads();
    #pragma unroll
    for (int i = 0; i < 2; ++i) {
        int r = i * 32 + sr;
        kreg[i] = *(const f16x8*)&K[(size_t)(kt0 + 64 + r) * D_MODEL + c0 + sc];
        vreg[i] = *(const f16x8*)&Vg[(size_t)(c0 + r) * S_LEN + kt0 + 64 + sc];
    }

    for (int it = 0; it < NITER; ++it) {
        const int buf = it & 1;
        const f16* ks = Ks[buf];
        const f16* vt = Vt[buf];

        f16x8 pf[2][2];       // [qt][kslot]
        #pragma unroll
        for (int s = 0; s < 4; ++s) {
            const int kslot = s >> 1, half = s & 1;
            const f16* kr = &ks[(kslot * 32 + half * 16 + l15) * LSTR];
            f16x8 kb0 = *(const f16x8*)&kr[quad * 8];
            f16x8 kb1 = *(const f16x8*)&kr[32 + quad * 8];
            #pragma unroll
            for (int qt = 0; qt < 2; ++qt) {
                f32x4 z = (f32x4){0.f, 0.f, 0.f, 0.f};
                z = __builtin_amdgcn_mfma_f32_16x16x32_f16(kb0, qa[qt][0], z, 0, 0, 0);
                z = __builtin_amdgcn_mfma_f32_16x16x32_f16(kb1, qa[qt][1], z, 0, 0, 0);
                float p0 = __builtin_amdgcn_exp2f(z[0]);
                float p1 = __builtin_amdgcn_exp2f(z[1]);
                float p2 = __builtin_amdgcn_exp2f(z[2]);
                float p3 = __builtin_amdgcn_exp2f(z[3]);
                lAcc[qt] += (p0 + p1) + (p2 + p3);
                pf[qt][kslot][half * 4 + 0] = (f16)p0;
                pf[qt][kslot][half * 4 + 1] = (f16)p1;
                pf[qt][kslot][half * 4 + 2] = (f16)p2;
                pf[qt][kslot][half * 4 + 3] = (f16)p3;
            }
        }

        #pragma unroll
        for (int mt = 0; mt < 4; ++mt) {
            #pragma unroll
            for (int ks2 = 0; ks2 < 2; ++ks2) {
                f16x8 va = *(const f16x8*)&vt[(mt * 16 + l15) * LSTR + ks2 * 32 + quad * 8];
                #pragma unroll
                for (int qt = 0; qt < 2; ++qt)
                    ctx[qt][mt] = __builtin_amdgcn_mfma_f32_16x16x32_f16(
                        va, pf[qt][ks2], ctx[qt][mt], 0, 0, 0);
            }
        }

        if (it + 1 < NITER) {
            #pragma unroll
            for (int i = 0; i < 2; ++i) {
                int r = i * 32 + sr;
                *(f16x8*)&Ks[1 - buf][(i * 32 + srk) * LSTR + sc] = kreg[i];
                *(f16x8*)&Vt[1 - buf][r * LSTR + sc] = vreg[i];
            }
        }
        __syncthreads();

        if (it + 2 < NITER) {
            int ktn = kt0 + (it + 2) * 64;
            #pragma unroll
            for (int i = 0; i < 2; ++i) {
                int r = i * 32 + sr;
                kreg[i] = *(const f16x8*)&K[(size_t)(ktn + r) * D_MODEL + c0 + sc];
                vreg[i] = *(const f16x8*)&Vg[(size_t)(c0 + r) * S_LEN + ktn + sc];
            }
        }
    }

    #pragma unroll
    for (int qt = 0; qt < 2; ++qt) {
        int qrow = q0 + w * 32 + qt * 16 + l15;
        #pragma unroll
        for (int mt = 0; mt < 4; ++mt) {
            f16x4 ov = { (f16)ctx[qt][mt][0], (f16)ctx[qt][mt][1],
                         (f16)ctx[qt][mt][2], (f16)ctx[qt][mt][3] };
            *(f16x4*)&Opart[(size_t)seg * SD + (size_t)qrow * D_MODEL
                            + c0 + mt * 16 + quad * 4] = ov;
        }
        float s = lAcc[qt];
        s += __shfl_xor(s, 16);
        s += __shfl_xor(s, 32);
        if (quad == 0)
            lsum[((size_t)seg * N_HEADS + h) * S_LEN + qrow] = s;
    }
}

// ---------------------------------------------------------------------------
// Combine 2 segments: Ctx = (O0 + O1) / (l0 + l1).  1536 blocks.
// Separate kernel — fusing into oproj staging regressed (R19).
// ---------------------------------------------------------------------------
__global__ __launch_bounds__(256) void combine_kernel(
    const f16* __restrict__ Opart, const float* __restrict__ lsum,
    f16* __restrict__ Ctx)
{
    const size_t SD = (size_t)S_LEN * D_MODEL;
    int tid = blockIdx.x * 256 + threadIdx.x;
    int idx = tid * 8;
    int row = idx / D_MODEL;
    int c   = idx % D_MODEL;
    int h   = c >> 6;
    float l0 = lsum[(size_t)h * S_LEN + row];
    float l1 = lsum[((size_t)N_HEADS + h) * S_LEN + row];
    float inv = 1.0f / (l0 + l1);
    f16x8 o0 = *(const f16x8*)&Opart[(size_t)row * D_MODEL + c];
    f16x8 o1 = *(const f16x8*)&Opart[SD + (size_t)row * D_MODEL + c];
    f16x8 r;
    #pragma unroll
    for (int j = 0; j < 8; ++j)
        r[j] = (f16)(((float)o0[j] + (float)o1[j]) * inv);
    *(f16x8*)&Ctx[(size_t)row * D_MODEL + c] = r;
}

// ---------------------------------------------------------------------------
// O-projection: out_f32 = Ctx @ Wto^T + bo.  128x128 tiles, 192 blocks.
// ---------------------------------------------------------------------------
__global__ __launch_bounds__(256) void oproj_kernel(
    const f16* __restrict__ Ctx, const f16* __restrict__ Wto,
    const float* __restrict__ bo, float* __restrict__ out)
{
    __shared__ f16 As[2 * GBOFF];
    __shared__ f16 Bs[2 * GBOFF];
    int bid = blockIdx.x;
    int row0 = (bid / 6) * 128, col0 = (bid % 6) * 128;

    f32x4 acc[4][4];
    #pragma unroll
    for (int i = 0; i < 4; ++i)
        #pragma unroll
        for (int j = 0; j < 4; ++j) acc[i][j] = (f32x4){0.f, 0.f, 0.f, 0.f};

    const int t = threadIdx.x;
    gemm128_core(Ctx, Wto, As, Bs, D_MODEL, row0, col0, t, acc);

    const int w = t >> 6, l = t & 63, quad = l >> 4, l15 = l & 15;
    const int wm = (w & 1) * 64, wn = (w >> 1) * 64;
    #pragma unroll
    for (int mt = 0; mt < 4; ++mt) {
        #pragma unroll
        for (int nt = 0; nt < 4; ++nt) {
            int col = col0 + wn + nt * 16 + l15;
            float b = bo[col];
            #pragma unroll
            for (int reg = 0; reg < 4; ++reg) {
                int row = row0 + wm + mt * 16 + quad * 4 + reg;
                out[(size_t)row * D_MODEL + col] = acc[mt][nt][reg] + b;
            }
        }
    }
}

// ---------------------------------------------------------------------------
extern "C" void kernel_launch(void* const* d_in, const int* in_sizes, int n_in,
                              void* d_out, int out_size, void* d_ws, size_t ws_size,
                              hipStream_t stream)
{
    const float* q  = (const float*)d_in[0];
    const float* k  = (const float*)d_in[1];
    const float* v  = (const float*)d_in[2];
    const float* Wq = (const float*)d_in[3];
    const float* bq = (const float*)d_in[4];
    const float* Wk = (const float*)d_in[5];
    const float* bk = (const float*)d_in[6];
    const float* Wv = (const float*)d_in[7];
    const float* bv = (const float*)d_in[8];
    const float* Wo = (const float*)d_in[9];
    const float* bo = (const float*)d_in[10];
    float* out = (float*)d_out;

    const size_t SD = (size_t)S_LEN * D_MODEL;
    const size_t DD = (size_t)D_MODEL * D_MODEL;
    f16* base   = (f16*)d_ws;
    f16* WtBase = base;                  // Wtq|Wtk|Wtv|Wto (4*DD)
    f16* Wto    = WtBase + 3 * DD;
    f16* Qp     = base + 4 * DD;
    f16* Kp     = Qp + SD;
    f16* Vpt    = Kp + SD;               // [D][S]
    f16* qh     = Vpt + SD;              // 3SD region, reused after qkv_gemm:
    f16* kh     = qh + SD;
    f16* vh     = kh + SD;
    f16* Opart  = qh;                    //   2*SD (aliases qh,kh)
    f16* Ctx    = qh + 2 * SD;           //   1*SD (aliases vh)
    float* lsum = (float*)(base + 4 * DD + 6 * SD);  // [2][H][S]

    prep_kernel<<<3 * 1536 + 4 * 144, 256, 0, stream>>>(
        q, k, v, qh, kh, vh, Wq, Wk, Wv, Wo, WtBase);

    qkv_gemm_kernel<<<3 * 192, 256, 0, stream>>>(
        qh, kh, vh, WtBase, bq, bk, bv, Qp, Kp, Vpt);

    dim3 gAttn(S_LEN / 128, N_HEADS, SEG);   // (32, 12, 2)
    flash_attn_part_kernel<<<gAttn, 256, 0, stream>>>(Qp, Kp, Vpt, Opart, lsum);

    combine_kernel<<<1536, 256, 0, stream>>>(Opart, lsum, Ctx);

    oproj_kernel<<<192, 256, 0, stream>>>(Ctx, Wto, bo, out);
}

// Round 12
// 216.948 us; speedup vs baseline: 1.2296x; 1.0337x over previous
//
#include <hip/hip_runtime.h>
#include <hip/hip_bf16.h>

// MHA: B=1, S=4096, D=768, H=12, DK=64.
// Round 22: R21 post-mortem — ping-pong GEMM core regressed (+14 us): 72 KiB
//   LDS halved co-resident blocks/CU; inter-block overlap was the latency
//   hider. REVERT core to R16 2-barrier form (210 us proven).
// NEW (one concept): GEMM tiles 128x128 -> 128x64. oproj was 192 blocks =
//   0.75/CU (64 CUs idle); now 384 = 1.5/CU. qkv 576 -> 1152 = 4.5/CU.
//   LDS 36 -> 27.6 KiB (5 blocks/CU capacity), VGPR ~48. Wave layout 2x2 of
//   64x32, acc[4][2]. Same barriers/staging as proven core; only B-panel
//   width halved. MFMA:ds 2.0 -> 1.33 — fine for latency-bound kernels.
// prep, flash (65 us), combine: exact R16.

constexpr int S_LEN = 4096;
constexpr int D_MODEL = 768;
constexpr int N_HEADS = 12;
constexpr int D_HEAD = 64;
constexpr int SEG = 2;
constexpr int SEG_LEN = S_LEN / SEG;   // 2048
constexpr int NITER = SEG_LEN / 64;    // 32

// Q pre-scale: (1/sqrt(64)) * log2(e)  -> scores in exp2 domain
#define QSCALE 0.180336880111120f

typedef _Float16 f16;
typedef __attribute__((ext_vector_type(8))) _Float16 f16x8;
typedef __attribute__((ext_vector_type(4))) _Float16 f16x4;
typedef __attribute__((ext_vector_type(4))) float f32x4;

// ---------------------------------------------------------------------------
// Merged prep: blocks [0, 4608) = f32->f16 convert of q,k,v (8 elem/thread);
//              blocks [4608, 5184) = W transpose+convert (144 blocks per W).
// ---------------------------------------------------------------------------
__global__ __launch_bounds__(256) void prep_kernel(
    const float* __restrict__ q, const float* __restrict__ k,
    const float* __restrict__ v, f16* __restrict__ qh,
    f16* __restrict__ kh, f16* __restrict__ vh,
    const float* __restrict__ W0, const float* __restrict__ W1,
    const float* __restrict__ W2, const float* __restrict__ W3,
    f16* __restrict__ WtBase)
{
    __shared__ float T[64][65];
    int bid = blockIdx.x;
    const int t = threadIdx.x;
    if (bid < 4608) {
        int g = bid / 1536, r = bid % 1536;
        const float* x = (g == 0) ? q : (g == 1) ? k : v;
        f16* y = (g == 0) ? qh : (g == 1) ? kh : vh;
        int i = (r * 256 + t) * 8;
        float4 a = *(const float4*)&x[i];
        float4 b = *(const float4*)&x[i + 4];
        f16x8 h = { (f16)a.x, (f16)a.y, (f16)a.z, (f16)a.w,
                    (f16)b.x, (f16)b.y, (f16)b.z, (f16)b.w };
        *(f16x8*)&y[i] = h;
        return;
    }
    bid -= 4608;
    int g = bid / 144, r = bid % 144;
    const float* W = (g == 0) ? W0 : (g == 1) ? W1 : (g == 2) ? W2 : W3;
    f16* Wt = WtBase + (size_t)g * D_MODEL * D_MODEL;
    const int r0 = (r / 12) * 64;
    const int c0 = (r % 12) * 64;
    #pragma unroll
    for (int i = 0; i < 16; ++i) {
        int e = t + 256 * i; int rr = e >> 6, cc = e & 63;
        T[rr][cc] = W[(size_t)(r0 + rr) * D_MODEL + c0 + cc];
    }
    __syncthreads();
    #pragma unroll
    for (int i = 0; i < 16; ++i) {
        int e = t + 256 * i; int rr = e >> 6, cc = e & 63;
        Wt[(size_t)(c0 + rr) * D_MODEL + r0 + cc] = (f16)T[cc][rr];
    }
}

// ---------------------------------------------------------------------------
// 128x64 GEMM core — R16's proven 2-barrier register-prefetch flow, with a
// 64-wide B panel. 4 waves as 2x2 of 64x32 wave-tiles; acc[4][2].
// Both operands k-contiguous (B^T form), BK=64. LDS stride 72.
// Staging is PURE f16 copies (R18/R19 lessons).
// ---------------------------------------------------------------------------
#define GSTR 72

__device__ __forceinline__ void gemm128x64_core(
    const f16* __restrict__ A, const f16* __restrict__ B,
    f16* As, f16* Bs, int K, int row0, int col0, int t, f32x4 acc[4][2])
{
    const int w = t >> 6, l = t & 63, quad = l >> 4, l15 = l & 15;
    const int wm = (w & 1) * 64, wn = (w >> 1) * 32;

    f16x8 pa[4], pb[2];
    #pragma unroll
    for (int i = 0; i < 4; ++i) {
        int idx = i * 256 + t;
        int r = idx >> 3, c = (idx & 7) * 8;
        pa[i] = *(const f16x8*)&A[(size_t)(row0 + r) * K + c];
    }
    #pragma unroll
    for (int i = 0; i < 2; ++i) {
        int idx = i * 256 + t;
        int r = idx >> 3, c = (idx & 7) * 8;
        pb[i] = *(const f16x8*)&B[(size_t)(col0 + r) * K + c];
    }

    for (int k0 = 0; k0 < K; k0 += 64) {
        __syncthreads();
        #pragma unroll
        for (int i = 0; i < 4; ++i) {
            int idx = i * 256 + t;
            int r = idx >> 3, c = (idx & 7) * 8;
            *(f16x8*)&As[r * GSTR + c] = pa[i];
        }
        #pragma unroll
        for (int i = 0; i < 2; ++i) {
            int idx = i * 256 + t;
            int r = idx >> 3, c = (idx & 7) * 8;
            *(f16x8*)&Bs[r * GSTR + c] = pb[i];
        }
        __syncthreads();

        int kn = k0 + 64;
        if (kn < K) {
            #pragma unroll
            for (int i = 0; i < 4; ++i) {
                int idx = i * 256 + t;
                int r = idx >> 3, c = (idx & 7) * 8;
                pa[i] = *(const f16x8*)&A[(size_t)(row0 + r) * K + kn + c];
            }
            #pragma unroll
            for (int i = 0; i < 2; ++i) {
                int idx = i * 256 + t;
                int r = idx >> 3, c = (idx & 7) * 8;
                pb[i] = *(const f16x8*)&B[(size_t)(col0 + r) * K + kn + c];
            }
        }

        #pragma unroll
        for (int kc = 0; kc < 2; ++kc) {
            f16x8 af[4], bf[2];
            #pragma unroll
            for (int mt = 0; mt < 4; ++mt)
                af[mt] = *(f16x8*)&As[(wm + mt * 16 + l15) * GSTR + kc * 32 + quad * 8];
            #pragma unroll
            for (int nt = 0; nt < 2; ++nt)
                bf[nt] = *(f16x8*)&Bs[(wn + nt * 16 + l15) * GSTR + kc * 32 + quad * 8];
            #pragma unroll
            for (int mt = 0; mt < 4; ++mt)
                #pragma unroll
                for (int nt = 0; nt < 2; ++nt)
                    acc[mt][nt] = __builtin_amdgcn_mfma_f32_16x16x32_f16(
                        af[mt], bf[nt], acc[mt][nt], 0, 0, 0);
        }
    }
}

// ---------------------------------------------------------------------------
// Batched QKV projections (f16 inputs), 128x64 tiles, 384 blocks per GEMM:
//  g0: Qp=(qh@Wtq^T+bq)*QSCALE [SxD]; g1: Kp [SxD]; g2: Vpt=Wtv@vh^T+bv [DxS].
// ---------------------------------------------------------------------------
__global__ __launch_bounds__(256) void qkv_gemm_kernel(
    const f16* __restrict__ qh, const f16* __restrict__ kh,
    const f16* __restrict__ vh, const f16* __restrict__ WtBase,
    const float* __restrict__ bq, const float* __restrict__ bk,
    const float* __restrict__ bv,
    f16* __restrict__ Qp, f16* __restrict__ Kp, f16* __restrict__ Vpt)
{
    __shared__ f16 As[128 * GSTR];
    __shared__ f16 Bs[64 * GSTR];
    const size_t DD = (size_t)D_MODEL * D_MODEL;
    int bid = blockIdx.x;
    int g = bid / 384, r = bid % 384;

    const f16 *A, *B; const float* bias; f16* Y;
    int N; bool biasRow; float scale;
    int row0, col0;
    if (g == 0) {
        A = qh; B = WtBase; bias = bq; Y = Qp;
        N = D_MODEL; biasRow = false; scale = QSCALE;
        row0 = (r / 12) * 128; col0 = (r % 12) * 64;
    } else if (g == 1) {
        A = kh; B = WtBase + DD; bias = bk; Y = Kp;
        N = D_MODEL; biasRow = false; scale = 1.0f;
        row0 = (r / 12) * 128; col0 = (r % 12) * 64;
    } else {
        A = WtBase + 2 * DD; B = vh; bias = bv; Y = Vpt;
        N = S_LEN; biasRow = true; scale = 1.0f;
        row0 = (r / 64) * 128; col0 = (r % 64) * 64;
    }

    f32x4 acc[4][2];
    #pragma unroll
    for (int i = 0; i < 4; ++i)
        #pragma unroll
        for (int j = 0; j < 2; ++j) acc[i][j] = (f32x4){0.f, 0.f, 0.f, 0.f};

    const int t = threadIdx.x;
    gemm128x64_core(A, B, As, Bs, D_MODEL, row0, col0, t, acc);

    const int w = t >> 6, l = t & 63, quad = l >> 4, l15 = l & 15;
    const int wm = (w & 1) * 64, wn = (w >> 1) * 32;
    #pragma unroll
    for (int mt = 0; mt < 4; ++mt) {
        #pragma unroll
        for (int nt = 0; nt < 2; ++nt) {
            int col = col0 + wn + nt * 16 + l15;
            #pragma unroll
            for (int reg = 0; reg < 4; ++reg) {
                int row = row0 + wm + mt * 16 + quad * 4 + reg;
                float b = biasRow ? bias[row] : bias[col];
                Y[(size_t)row * N + col] = (f16)((acc[mt][nt][reg] + b) * scale);
            }
        }
    }
}

// ---------------------------------------------------------------------------
// Flash attention — EXACT R16 structure (65-66 us proven): 256 thr, 4 waves,
// qt=2, SEG=2, KVBLK=64, ping-pong K/V LDS, one barrier per k-iter,
// K rows sigma-permuted at LDS-store so PV runs full-rate 16x16x32 MFMA.
// ---------------------------------------------------------------------------
#define LSTR 72

__global__ __launch_bounds__(256, 4) void flash_attn_part_kernel(
    const f16* __restrict__ Q, const f16* __restrict__ K,
    const f16* __restrict__ Vg, f16* __restrict__ Opart,
    float* __restrict__ lsum)
{
    __shared__ f16 Ks[2][64 * LSTR];
    __shared__ f16 Vt[2][64 * LSTR];

    const int t    = threadIdx.x;
    const int w    = t >> 6;
    const int l    = t & 63;
    const int quad = l >> 4;
    const int l15  = l & 15;
    const int h    = blockIdx.y;
    const int q0   = blockIdx.x * 128;
    const int seg  = blockIdx.z;
    const int c0   = h * D_HEAD;
    const size_t SD = (size_t)S_LEN * D_MODEL;

    const int sr = t >> 3;            // row 0..31  (r = i*32+sr)
    const int sc = (t & 7) * 8;       // f16 col chunk
    // sigma: kv = q*8 + h2*4 + rr -> row = h2*16 + q*4 + rr
    const int srk = ((sr & 4) << 2) | ((sr & 24) >> 1) | (sr & 3);

    f16x8 qa[2][2];
    #pragma unroll
    for (int qt = 0; qt < 2; ++qt) {
        const f16* qrow = Q + (size_t)(q0 + w * 32 + qt * 16 + l15) * D_MODEL + c0;
        qa[qt][0] = *(const f16x8*)&qrow[quad * 8];
        qa[qt][1] = *(const f16x8*)&qrow[32 + quad * 8];
    }

    f32x4 ctx[2][4];
    float lAcc[2] = {0.f, 0.f};
    #pragma unroll
    for (int qt = 0; qt < 2; ++qt)
        #pragma unroll
        for (int i = 0; i < 4; ++i) ctx[qt][i] = (f32x4){0.f, 0.f, 0.f, 0.f};

    const int kt0 = seg * SEG_LEN;

    f16x8 kreg[2], vreg[2];
    #pragma unroll
    for (int i = 0; i < 2; ++i) {
        int r = i * 32 + sr;
        kreg[i] = *(const f16x8*)&K[(size_t)(kt0 + r) * D_MODEL + c0 + sc];
        vreg[i] = *(const f16x8*)&Vg[(size_t)(c0 + r) * S_LEN + kt0 + sc];
    }
    #pragma unroll
    for (int i = 0; i < 2; ++i) {
        int r = i * 32 + sr;
        *(f16x8*)&Ks[0][(i * 32 + srk) * LSTR + sc] = kreg[i];
        *(f16x8*)&Vt[0][r * LSTR + sc] = vreg[i];
    }
    __syncthreads();
    #pragma unroll
    for (int i = 0; i < 2; ++i) {
        int r = i * 32 + sr;
        kreg[i] = *(const f16x8*)&K[(size_t)(kt0 + 64 + r) * D_MODEL + c0 + sc];
        vreg[i] = *(const f16x8*)&Vg[(size_t)(c0 + r) * S_LEN + kt0 + 64 + sc];
    }

    for (int it = 0; it < NITER; ++it) {
        const int buf = it & 1;
        const f16* ks = Ks[buf];
        const f16* vt = Vt[buf];

        f16x8 pf[2][2];       // [qt][kslot]
        #pragma unroll
        for (int s = 0; s < 4; ++s) {
            const int kslot = s >> 1, half = s & 1;
            const f16* kr = &ks[(kslot * 32 + half * 16 + l15) * LSTR];
            f16x8 kb0 = *(const f16x8*)&kr[quad * 8];
            f16x8 kb1 = *(const f16x8*)&kr[32 + quad * 8];
            #pragma unroll
            for (int qt = 0; qt < 2; ++qt) {
                f32x4 z = (f32x4){0.f, 0.f, 0.f, 0.f};
                z = __builtin_amdgcn_mfma_f32_16x16x32_f16(kb0, qa[qt][0], z, 0, 0, 0);
                z = __builtin_amdgcn_mfma_f32_16x16x32_f16(kb1, qa[qt][1], z, 0, 0, 0);
                float p0 = __builtin_amdgcn_exp2f(z[0]);
                float p1 = __builtin_amdgcn_exp2f(z[1]);
                float p2 = __builtin_amdgcn_exp2f(z[2]);
                float p3 = __builtin_amdgcn_exp2f(z[3]);
                lAcc[qt] += (p0 + p1) + (p2 + p3);
                pf[qt][kslot][half * 4 + 0] = (f16)p0;
                pf[qt][kslot][half * 4 + 1] = (f16)p1;
                pf[qt][kslot][half * 4 + 2] = (f16)p2;
                pf[qt][kslot][half * 4 + 3] = (f16)p3;
            }
        }

        #pragma unroll
        for (int mt = 0; mt < 4; ++mt) {
            #pragma unroll
            for (int ks2 = 0; ks2 < 2; ++ks2) {
                f16x8 va = *(const f16x8*)&vt[(mt * 16 + l15) * LSTR + ks2 * 32 + quad * 8];
                #pragma unroll
                for (int qt = 0; qt < 2; ++qt)
                    ctx[qt][mt] = __builtin_amdgcn_mfma_f32_16x16x32_f16(
                        va, pf[qt][ks2], ctx[qt][mt], 0, 0, 0);
            }
        }

        if (it + 1 < NITER) {
            #pragma unroll
            for (int i = 0; i < 2; ++i) {
                int r = i * 32 + sr;
                *(f16x8*)&Ks[1 - buf][(i * 32 + srk) * LSTR + sc] = kreg[i];
                *(f16x8*)&Vt[1 - buf][r * LSTR + sc] = vreg[i];
            }
        }
        __syncthreads();

        if (it + 2 < NITER) {
            int ktn = kt0 + (it + 2) * 64;
            #pragma unroll
            for (int i = 0; i < 2; ++i) {
                int r = i * 32 + sr;
                kreg[i] = *(const f16x8*)&K[(size_t)(ktn + r) * D_MODEL + c0 + sc];
                vreg[i] = *(const f16x8*)&Vg[(size_t)(c0 + r) * S_LEN + ktn + sc];
            }
        }
    }

    #pragma unroll
    for (int qt = 0; qt < 2; ++qt) {
        int qrow = q0 + w * 32 + qt * 16 + l15;
        #pragma unroll
        for (int mt = 0; mt < 4; ++mt) {
            f16x4 ov = { (f16)ctx[qt][mt][0], (f16)ctx[qt][mt][1],
                         (f16)ctx[qt][mt][2], (f16)ctx[qt][mt][3] };
            *(f16x4*)&Opart[(size_t)seg * SD + (size_t)qrow * D_MODEL
                            + c0 + mt * 16 + quad * 4] = ov;
        }
        float s = lAcc[qt];
        s += __shfl_xor(s, 16);
        s += __shfl_xor(s, 32);
        if (quad == 0)
            lsum[((size_t)seg * N_HEADS + h) * S_LEN + qrow] = s;
    }
}

// ---------------------------------------------------------------------------
// Combine 2 segments: Ctx = (O0 + O1) / (l0 + l1).  1536 blocks.
// Separate kernel — fusing into oproj staging regressed (R19).
// ---------------------------------------------------------------------------
__global__ __launch_bounds__(256) void combine_kernel(
    const f16* __restrict__ Opart, const float* __restrict__ lsum,
    f16* __restrict__ Ctx)
{
    const size_t SD = (size_t)S_LEN * D_MODEL;
    int tid = blockIdx.x * 256 + threadIdx.x;
    int idx = tid * 8;
    int row = idx / D_MODEL;
    int c   = idx % D_MODEL;
    int h   = c >> 6;
    float l0 = lsum[(size_t)h * S_LEN + row];
    float l1 = lsum[((size_t)N_HEADS + h) * S_LEN + row];
    float inv = 1.0f / (l0 + l1);
    f16x8 o0 = *(const f16x8*)&Opart[(size_t)row * D_MODEL + c];
    f16x8 o1 = *(const f16x8*)&Opart[SD + (size_t)row * D_MODEL + c];
    f16x8 r;
    #pragma unroll
    for (int j = 0; j < 8; ++j)
        r[j] = (f16)(((float)o0[j] + (float)o1[j]) * inv);
    *(f16x8*)&Ctx[(size_t)row * D_MODEL + c] = r;
}

// ---------------------------------------------------------------------------
// O-projection: out_f32 = Ctx @ Wto^T + bo.  128x64 tiles, 384 blocks.
// ---------------------------------------------------------------------------
__global__ __launch_bounds__(256) void oproj_kernel(
    const f16* __restrict__ Ctx, const f16* __restrict__ Wto,
    const float* __restrict__ bo, float* __restrict__ out)
{
    __shared__ f16 As[128 * GSTR];
    __shared__ f16 Bs[64 * GSTR];
    int bid = blockIdx.x;
    int row0 = (bid / 12) * 128, col0 = (bid % 12) * 64;

    f32x4 acc[4][2];
    #pragma unroll
    for (int i = 0; i < 4; ++i)
        #pragma unroll
        for (int j = 0; j < 2; ++j) acc[i][j] = (f32x4){0.f, 0.f, 0.f, 0.f};

    const int t = threadIdx.x;
    gemm128x64_core(Ctx, Wto, As, Bs, D_MODEL, row0, col0, t, acc);

    const int w = t >> 6, l = t & 63, quad = l >> 4, l15 = l & 15;
    const int wm = (w & 1) * 64, wn = (w >> 1) * 32;
    #pragma unroll
    for (int mt = 0; mt < 4; ++mt) {
        #pragma unroll
        for (int nt = 0; nt < 2; ++nt) {
            int col = col0 + wn + nt * 16 + l15;
            float b = bo[col];
            #pragma unroll
            for (int reg = 0; reg < 4; ++reg) {
                int row = row0 + wm + mt * 16 + quad * 4 + reg;
                out[(size_t)row * D_MODEL + col] = acc[mt][nt][reg] + b;
            }
        }
    }
}

// ---------------------------------------------------------------------------
extern "C" void kernel_launch(void* const* d_in, const int* in_sizes, int n_in,
                              void* d_out, int out_size, void* d_ws, size_t ws_size,
                              hipStream_t stream)
{
    const float* q  = (const float*)d_in[0];
    const float* k  = (const float*)d_in[1];
    const float* v  = (const float*)d_in[2];
    const float* Wq = (const float*)d_in[3];
    const float* bq = (const float*)d_in[4];
    const float* Wk = (const float*)d_in[5];
    const float* bk = (const float*)d_in[6];
    const float* Wv = (const float*)d_in[7];
    const float* bv = (const float*)d_in[8];
    const float* Wo = (const float*)d_in[9];
    const float* bo = (const float*)d_in[10];
    float* out = (float*)d_out;

    const size_t SD = (size_t)S_LEN * D_MODEL;
    const size_t DD = (size_t)D_MODEL * D_MODEL;
    f16* base   = (f16*)d_ws;
    f16* WtBase = base;                  // Wtq|Wtk|Wtv|Wto (4*DD)
    f16* Wto    = WtBase + 3 * DD;
    f16* Qp     = base + 4 * DD;
    f16* Kp     = Qp + SD;
    f16* Vpt    = Kp + SD;               // [D][S]
    f16* qh     = Vpt + SD;              // 3SD region, reused after qkv_gemm:
    f16* kh     = qh + SD;
    f16* vh     = kh + SD;
    f16* Opart  = qh;                    //   2*SD (aliases qh,kh)
    f16* Ctx    = qh + 2 * SD;           //   1*SD (aliases vh)
    float* lsum = (float*)(base + 4 * DD + 6 * SD);  // [2][H][S]

    prep_kernel<<<3 * 1536 + 4 * 144, 256, 0, stream>>>(
        q, k, v, qh, kh, vh, Wq, Wk, Wv, Wo, WtBase);

    qkv_gemm_kernel<<<3 * 384, 256, 0, stream>>>(
        qh, kh, vh, WtBase, bq, bk, bv, Qp, Kp, Vpt);

    dim3 gAttn(S_LEN / 128, N_HEADS, SEG);   // (32, 12, 2)
    flash_attn_part_kernel<<<gAttn, 256, 0, stream>>>(Qp, Kp, Vpt, Opart, lsum);

    combine_kernel<<<1536, 256, 0, stream>>>(Opart, lsum, Ctx);

    oproj_kernel<<<384, 256, 0, stream>>>(Ctx, Wto, bo, out);
}

// Round 13
// 216.944 us; speedup vs baseline: 1.2296x; 1.0000x over previous
//
#include <hip/hip_runtime.h>
#include <hip/hip_bf16.h>

// MHA: B=1, S=4096, D=768, H=12, DK=64.
// Round 23: R22 post-mortem — 128x64 tiles regressed (+7 us: 2x A-panel
//   re-reads). Five structural edits to non-flash all lost; the constant is
//   the reg-staging path itself. NEW (one concept): qkv GEMM core switched
//   to m97-style __builtin_amdgcn_global_load_lds(16B) staging:
//   - LDS linear [128][64] (gload_lds forbids padding), single 32 KB buffer
//   - XOR swizzle BOTH sides (rule #21): global source col ^= (row&7)*8,
//     read col ^= (row&7)*8, LDS write stays linear -> ds_read 2-way (free)
//   - 2-barrier loop; cross-block overlap at 2.25 blk/CU covers the drain.
//   Guide evidence: m93 517 TF (reg-staged) -> m97 874 TF (gload_lds w=16).
// oproj KEEPS R16 reg-prefetch core (0.75 blk/CU has no cross-block overlap).
// prep, flash (65 us local optimum), combine: exact R16.

constexpr int S_LEN = 4096;
constexpr int D_MODEL = 768;
constexpr int N_HEADS = 12;
constexpr int D_HEAD = 64;
constexpr int SEG = 2;
constexpr int SEG_LEN = S_LEN / SEG;   // 2048
constexpr int NITER = SEG_LEN / 64;    // 32

// Q pre-scale: (1/sqrt(64)) * log2(e)  -> scores in exp2 domain
#define QSCALE 0.180336880111120f

typedef _Float16 f16;
typedef __attribute__((ext_vector_type(8))) _Float16 f16x8;
typedef __attribute__((ext_vector_type(4))) _Float16 f16x4;
typedef __attribute__((ext_vector_type(4))) float f32x4;

// ---------------------------------------------------------------------------
// Merged prep: blocks [0, 4608) = f32->f16 convert of q,k,v (8 elem/thread);
//              blocks [4608, 5184) = W transpose+convert (144 blocks per W).
// ---------------------------------------------------------------------------
__global__ __launch_bounds__(256) void prep_kernel(
    const float* __restrict__ q, const float* __restrict__ k,
    const float* __restrict__ v, f16* __restrict__ qh,
    f16* __restrict__ kh, f16* __restrict__ vh,
    const float* __restrict__ W0, const float* __restrict__ W1,
    const float* __restrict__ W2, const float* __restrict__ W3,
    f16* __restrict__ WtBase)
{
    __shared__ float T[64][65];
    int bid = blockIdx.x;
    const int t = threadIdx.x;
    if (bid < 4608) {
        int g = bid / 1536, r = bid % 1536;
        const float* x = (g == 0) ? q : (g == 1) ? k : v;
        f16* y = (g == 0) ? qh : (g == 1) ? kh : vh;
        int i = (r * 256 + t) * 8;
        float4 a = *(const float4*)&x[i];
        float4 b = *(const float4*)&x[i + 4];
        f16x8 h = { (f16)a.x, (f16)a.y, (f16)a.z, (f16)a.w,
                    (f16)b.x, (f16)b.y, (f16)b.z, (f16)b.w };
        *(f16x8*)&y[i] = h;
        return;
    }
    bid -= 4608;
    int g = bid / 144, r = bid % 144;
    const float* W = (g == 0) ? W0 : (g == 1) ? W1 : (g == 2) ? W2 : W3;
    f16* Wt = WtBase + (size_t)g * D_MODEL * D_MODEL;
    const int r0 = (r / 12) * 64;
    const int c0 = (r % 12) * 64;
    #pragma unroll
    for (int i = 0; i < 16; ++i) {
        int e = t + 256 * i; int rr = e >> 6, cc = e & 63;
        T[rr][cc] = W[(size_t)(r0 + rr) * D_MODEL + c0 + cc];
    }
    __syncthreads();
    #pragma unroll
    for (int i = 0; i < 16; ++i) {
        int e = t + 256 * i; int rr = e >> 6, cc = e & 63;
        Wt[(size_t)(c0 + rr) * D_MODEL + r0 + cc] = (f16)T[cc][rr];
    }
}

// ---------------------------------------------------------------------------
// R23 qkv core: 128x128 tile, global_load_lds(16B) staging, linear LDS
// [128][64] per panel, XOR both-sides swizzle (src col and read col).
// 2-barrier loop (m97 structure). 4 waves 2x2; acc[4][4].
// ---------------------------------------------------------------------------
__device__ __forceinline__ void gemm128_lds_core(
    const f16* __restrict__ A, const f16* __restrict__ B,
    f16* As, f16* Bs, int K, int row0, int col0, int t, f32x4 acc[4][4])
{
    const int w = t >> 6, l = t & 63, quad = l >> 4, l15 = l & 15;
    const int wm = (w & 1) * 64, wn = (w >> 1) * 64;
    const int srow = t >> 3;            // 0..31 (rows within a call-group)
    const int scol = (t & 7) * 8;       // base f16 col chunk

    for (int k0 = 0; k0 < K; k0 += 64) {
        // stage A and B panels: 4 calls each, lane-linear LDS dest,
        // pre-swizzled global source column (c ^ (row&7)*8)
        #pragma unroll
        for (int i = 0; i < 4; ++i) {
            int r = i * 32 + srow;
            int cs = scol ^ ((r & 7) * 8);
            __builtin_amdgcn_global_load_lds(
                (const __attribute__((address_space(1))) void*)
                    &A[(size_t)(row0 + r) * K + k0 + cs],
                (__attribute__((address_space(3))) void*)
                    &As[i * 2048 + w * 512], 16, 0, 0);
            __builtin_amdgcn_global_load_lds(
                (const __attribute__((address_space(1))) void*)
                    &B[(size_t)(col0 + r) * K + k0 + cs],
                (__attribute__((address_space(3))) void*)
                    &Bs[i * 2048 + w * 512], 16, 0, 0);
        }
        __syncthreads();   // compiler drains vmcnt before the barrier

        #pragma unroll
        for (int kc = 0; kc < 2; ++kc) {
            f16x8 af[4], bf[4];
            #pragma unroll
            for (int mt = 0; mt < 4; ++mt) {
                int rowA = wm + mt * 16 + l15;
                af[mt] = *(const f16x8*)
                    &As[rowA * 64 + ((kc * 32 + quad * 8) ^ ((rowA & 7) * 8))];
            }
            #pragma unroll
            for (int nt = 0; nt < 4; ++nt) {
                int rowB = wn + nt * 16 + l15;
                bf[nt] = *(const f16x8*)
                    &Bs[rowB * 64 + ((kc * 32 + quad * 8) ^ ((rowB & 7) * 8))];
            }
            #pragma unroll
            for (int mt = 0; mt < 4; ++mt)
                #pragma unroll
                for (int nt = 0; nt < 4; ++nt)
                    acc[mt][nt] = __builtin_amdgcn_mfma_f32_16x16x32_f16(
                        af[mt], bf[nt], acc[mt][nt], 0, 0, 0);
        }
        __syncthreads();   // protect LDS before next-tile overwrite
    }
}

// ---------------------------------------------------------------------------
// R16 core (register-prefetch, padded LDS) — kept for oproj (0.75 blk/CU:
// within-block overlap is the only latency hider there).
// ---------------------------------------------------------------------------
#define GSTR 72

__device__ __forceinline__ void gemm128_core(
    const f16* __restrict__ A, const f16* __restrict__ B,
    f16* As, f16* Bs, int K, int row0, int col0, int t, f32x4 acc[4][4])
{
    const int w = t >> 6, l = t & 63, quad = l >> 4, l15 = l & 15;
    const int wm = (w & 1) * 64, wn = (w >> 1) * 64;

    f16x8 pa[4], pb[4];
    #pragma unroll
    for (int i = 0; i < 4; ++i) {
        int idx = i * 256 + t;
        int r = idx >> 3, c = (idx & 7) * 8;
        pa[i] = *(const f16x8*)&A[(size_t)(row0 + r) * K + c];
        pb[i] = *(const f16x8*)&B[(size_t)(col0 + r) * K + c];
    }

    for (int k0 = 0; k0 < K; k0 += 64) {
        __syncthreads();
        #pragma unroll
        for (int i = 0; i < 4; ++i) {
            int idx = i * 256 + t;
            int r = idx >> 3, c = (idx & 7) * 8;
            *(f16x8*)&As[r * GSTR + c] = pa[i];
            *(f16x8*)&Bs[r * GSTR + c] = pb[i];
        }
        __syncthreads();

        int kn = k0 + 64;
        if (kn < K) {
            #pragma unroll
            for (int i = 0; i < 4; ++i) {
                int idx = i * 256 + t;
                int r = idx >> 3, c = (idx & 7) * 8;
                pa[i] = *(const f16x8*)&A[(size_t)(row0 + r) * K + kn + c];
                pb[i] = *(const f16x8*)&B[(size_t)(col0 + r) * K + kn + c];
            }
        }

        #pragma unroll
        for (int kc = 0; kc < 2; ++kc) {
            f16x8 af[4], bf[4];
            #pragma unroll
            for (int mt = 0; mt < 4; ++mt)
                af[mt] = *(f16x8*)&As[(wm + mt * 16 + l15) * GSTR + kc * 32 + quad * 8];
            #pragma unroll
            for (int nt = 0; nt < 4; ++nt)
                bf[nt] = *(f16x8*)&Bs[(wn + nt * 16 + l15) * GSTR + kc * 32 + quad * 8];
            #pragma unroll
            for (int mt = 0; mt < 4; ++mt)
                #pragma unroll
                for (int nt = 0; nt < 4; ++nt)
                    acc[mt][nt] = __builtin_amdgcn_mfma_f32_16x16x32_f16(
                        af[mt], bf[nt], acc[mt][nt], 0, 0, 0);
        }
    }
}

// ---------------------------------------------------------------------------
// Batched QKV projections (f16 inputs), 128x128 tiles, 192 blocks per GEMM:
//  g0: Qp=(qh@Wtq^T+bq)*QSCALE [SxD]; g1: Kp [SxD]; g2: Vpt=Wtv@vh^T+bv [DxS].
// R23: gload_lds staging core.
// ---------------------------------------------------------------------------
__global__ __launch_bounds__(256) void qkv_gemm_kernel(
    const f16* __restrict__ qh, const f16* __restrict__ kh,
    const f16* __restrict__ vh, const f16* __restrict__ WtBase,
    const float* __restrict__ bq, const float* __restrict__ bk,
    const float* __restrict__ bv,
    f16* __restrict__ Qp, f16* __restrict__ Kp, f16* __restrict__ Vpt)
{
    __shared__ f16 As[128 * 64];
    __shared__ f16 Bs[128 * 64];
    const size_t DD = (size_t)D_MODEL * D_MODEL;
    int bid = blockIdx.x;
    int g = bid / 192, r = bid % 192;

    const f16 *A, *B; const float* bias; f16* Y;
    int N; bool biasRow; float scale;
    int row0, col0;
    if (g == 0) {
        A = qh; B = WtBase; bias = bq; Y = Qp;
        N = D_MODEL; biasRow = false; scale = QSCALE;
        row0 = (r / 6) * 128; col0 = (r % 6) * 128;
    } else if (g == 1) {
        A = kh; B = WtBase + DD; bias = bk; Y = Kp;
        N = D_MODEL; biasRow = false; scale = 1.0f;
        row0 = (r / 6) * 128; col0 = (r % 6) * 128;
    } else {
        A = WtBase + 2 * DD; B = vh; bias = bv; Y = Vpt;
        N = S_LEN; biasRow = true; scale = 1.0f;
        row0 = (r / 32) * 128; col0 = (r % 32) * 128;
    }

    f32x4 acc[4][4];
    #pragma unroll
    for (int i = 0; i < 4; ++i)
        #pragma unroll
        for (int j = 0; j < 4; ++j) acc[i][j] = (f32x4){0.f, 0.f, 0.f, 0.f};

    const int t = threadIdx.x;
    gemm128_lds_core(A, B, As, Bs, D_MODEL, row0, col0, t, acc);

    const int w = t >> 6, l = t & 63, quad = l >> 4, l15 = l & 15;
    const int wm = (w & 1) * 64, wn = (w >> 1) * 64;
    #pragma unroll
    for (int mt = 0; mt < 4; ++mt) {
        #pragma unroll
        for (int nt = 0; nt < 4; ++nt) {
            int col = col0 + wn + nt * 16 + l15;
            #pragma unroll
            for (int reg = 0; reg < 4; ++reg) {
                int row = row0 + wm + mt * 16 + quad * 4 + reg;
                float b = biasRow ? bias[row] : bias[col];
                Y[(size_t)row * N + col] = (f16)((acc[mt][nt][reg] + b) * scale);
            }
        }
    }
}

// ---------------------------------------------------------------------------
// Flash attention — EXACT R16 structure (65-66 us proven): 256 thr, 4 waves,
// qt=2, SEG=2, KVBLK=64, ping-pong K/V LDS, one barrier per k-iter,
// K rows sigma-permuted at LDS-store so PV runs full-rate 16x16x32 MFMA.
// ---------------------------------------------------------------------------
#define LSTR 72

__global__ __launch_bounds__(256, 4) void flash_attn_part_kernel(
    const f16* __restrict__ Q, const f16* __restrict__ K,
    const f16* __restrict__ Vg, f16* __restrict__ Opart,
    float* __restrict__ lsum)
{
    __shared__ f16 Ks[2][64 * LSTR];
    __shared__ f16 Vt[2][64 * LSTR];

    const int t    = threadIdx.x;
    const int w    = t >> 6;
    const int l    = t & 63;
    const int quad = l >> 4;
    const int l15  = l & 15;
    const int h    = blockIdx.y;
    const int q0   = blockIdx.x * 128;
    const int seg  = blockIdx.z;
    const int c0   = h * D_HEAD;
    const size_t SD = (size_t)S_LEN * D_MODEL;

    const int sr = t >> 3;            // row 0..31  (r = i*32+sr)
    const int sc = (t & 7) * 8;       // f16 col chunk
    // sigma: kv = q*8 + h2*4 + rr -> row = h2*16 + q*4 + rr
    const int srk = ((sr & 4) << 2) | ((sr & 24) >> 1) | (sr & 3);

    f16x8 qa[2][2];
    #pragma unroll
    for (int qt = 0; qt < 2; ++qt) {
        const f16* qrow = Q + (size_t)(q0 + w * 32 + qt * 16 + l15) * D_MODEL + c0;
        qa[qt][0] = *(const f16x8*)&qrow[quad * 8];
        qa[qt][1] = *(const f16x8*)&qrow[32 + quad * 8];
    }

    f32x4 ctx[2][4];
    float lAcc[2] = {0.f, 0.f};
    #pragma unroll
    for (int qt = 0; qt < 2; ++qt)
        #pragma unroll
        for (int i = 0; i < 4; ++i) ctx[qt][i] = (f32x4){0.f, 0.f, 0.f, 0.f};

    const int kt0 = seg * SEG_LEN;

    f16x8 kreg[2], vreg[2];
    #pragma unroll
    for (int i = 0; i < 2; ++i) {
        int r = i * 32 + sr;
        kreg[i] = *(const f16x8*)&K[(size_t)(kt0 + r) * D_MODEL + c0 + sc];
        vreg[i] = *(const f16x8*)&Vg[(size_t)(c0 + r) * S_LEN + kt0 + sc];
    }
    #pragma unroll
    for (int i = 0; i < 2; ++i) {
        int r = i * 32 + sr;
        *(f16x8*)&Ks[0][(i * 32 + srk) * LSTR + sc] = kreg[i];
        *(f16x8*)&Vt[0][r * LSTR + sc] = vreg[i];
    }
    __syncthreads();
    #pragma unroll
    for (int i = 0; i < 2; ++i) {
        int r = i * 32 + sr;
        kreg[i] = *(const f16x8*)&K[(size_t)(kt0 + 64 + r) * D_MODEL + c0 + sc];
        vreg[i] = *(const f16x8*)&Vg[(size_t)(c0 + r) * S_LEN + kt0 + 64 + sc];
    }

    for (int it = 0; it < NITER; ++it) {
        const int buf = it & 1;
        const f16* ks = Ks[buf];
        const f16* vt = Vt[buf];

        f16x8 pf[2][2];       // [qt][kslot]
        #pragma unroll
        for (int s = 0; s < 4; ++s) {
            const int kslot = s >> 1, half = s & 1;
            const f16* kr = &ks[(kslot * 32 + half * 16 + l15) * LSTR];
            f16x8 kb0 = *(const f16x8*)&kr[quad * 8];
            f16x8 kb1 = *(const f16x8*)&kr[32 + quad * 8];
            #pragma unroll
            for (int qt = 0; qt < 2; ++qt) {
                f32x4 z = (f32x4){0.f, 0.f, 0.f, 0.f};
                z = __builtin_amdgcn_mfma_f32_16x16x32_f16(kb0, qa[qt][0], z, 0, 0, 0);
                z = __builtin_amdgcn_mfma_f32_16x16x32_f16(kb1, qa[qt][1], z, 0, 0, 0);
                float p0 = __builtin_amdgcn_exp2f(z[0]);
                float p1 = __builtin_amdgcn_exp2f(z[1]);
                float p2 = __builtin_amdgcn_exp2f(z[2]);
                float p3 = __builtin_amdgcn_exp2f(z[3]);
                lAcc[qt] += (p0 + p1) + (p2 + p3);
                pf[qt][kslot][half * 4 + 0] = (f16)p0;
                pf[qt][kslot][half * 4 + 1] = (f16)p1;
                pf[qt][kslot][half * 4 + 2] = (f16)p2;
                pf[qt][kslot][half * 4 + 3] = (f16)p3;
            }
        }

        #pragma unroll
        for (int mt = 0; mt < 4; ++mt) {
            #pragma unroll
            for (int ks2 = 0; ks2 < 2; ++ks2) {
                f16x8 va = *(const f16x8*)&vt[(mt * 16 + l15) * LSTR + ks2 * 32 + quad * 8];
                #pragma unroll
                for (int qt = 0; qt < 2; ++qt)
                    ctx[qt][mt] = __builtin_amdgcn_mfma_f32_16x16x32_f16(
                        va, pf[qt][ks2], ctx[qt][mt], 0, 0, 0);
            }
        }

        if (it + 1 < NITER) {
            #pragma unroll
            for (int i = 0; i < 2; ++i) {
                int r = i * 32 + sr;
                *(f16x8*)&Ks[1 - buf][(i * 32 + srk) * LSTR + sc] = kreg[i];
                *(f16x8*)&Vt[1 - buf][r * LSTR + sc] = vreg[i];
            }
        }
        __syncthreads();

        if (it + 2 < NITER) {
            int ktn = kt0 + (it + 2) * 64;
            #pragma unroll
            for (int i = 0; i < 2; ++i) {
                int r = i * 32 + sr;
                kreg[i] = *(const f16x8*)&K[(size_t)(ktn + r) * D_MODEL + c0 + sc];
                vreg[i] = *(const f16x8*)&Vg[(size_t)(c0 + r) * S_LEN + ktn + sc];
            }
        }
    }

    #pragma unroll
    for (int qt = 0; qt < 2; ++qt) {
        int qrow = q0 + w * 32 + qt * 16 + l15;
        #pragma unroll
        for (int mt = 0; mt < 4; ++mt) {
            f16x4 ov = { (f16)ctx[qt][mt][0], (f16)ctx[qt][mt][1],
                         (f16)ctx[qt][mt][2], (f16)ctx[qt][mt][3] };
            *(f16x4*)&Opart[(size_t)seg * SD + (size_t)qrow * D_MODEL
                            + c0 + mt * 16 + quad * 4] = ov;
        }
        float s = lAcc[qt];
        s += __shfl_xor(s, 16);
        s += __shfl_xor(s, 32);
        if (quad == 0)
            lsum[((size_t)seg * N_HEADS + h) * S_LEN + qrow] = s;
    }
}

// ---------------------------------------------------------------------------
// Combine 2 segments: Ctx = (O0 + O1) / (l0 + l1).  1536 blocks.
// ---------------------------------------------------------------------------
__global__ __launch_bounds__(256) void combine_kernel(
    const f16* __restrict__ Opart, const float* __restrict__ lsum,
    f16* __restrict__ Ctx)
{
    const size_t SD = (size_t)S_LEN * D_MODEL;
    int tid = blockIdx.x * 256 + threadIdx.x;
    int idx = tid * 8;
    int row = idx / D_MODEL;
    int c   = idx % D_MODEL;
    int h   = c >> 6;
    float l0 = lsum[(size_t)h * S_LEN + row];
    float l1 = lsum[((size_t)N_HEADS + h) * S_LEN + row];
    float inv = 1.0f / (l0 + l1);
    f16x8 o0 = *(const f16x8*)&Opart[(size_t)row * D_MODEL + c];
    f16x8 o1 = *(const f16x8*)&Opart[SD + (size_t)row * D_MODEL + c];
    f16x8 r;
    #pragma unroll
    for (int j = 0; j < 8; ++j)
        r[j] = (f16)(((float)o0[j] + (float)o1[j]) * inv);
    *(f16x8*)&Ctx[(size_t)row * D_MODEL + c] = r;
}

// ---------------------------------------------------------------------------
// O-projection: out_f32 = Ctx @ Wto^T + bo.  128x128 tiles, 192 blocks.
// Keeps R16 reg-prefetch core.
// ---------------------------------------------------------------------------
__global__ __launch_bounds__(256) void oproj_kernel(
    const f16* __restrict__ Ctx, const f16* __restrict__ Wto,
    const float* __restrict__ bo, float* __restrict__ out)
{
    __shared__ f16 As[128 * GSTR];
    __shared__ f16 Bs[128 * GSTR];
    int bid = blockIdx.x;
    int row0 = (bid / 6) * 128, col0 = (bid % 6) * 128;

    f32x4 acc[4][4];
    #pragma unroll
    for (int i = 0; i < 4; ++i)
        #pragma unroll
        for (int j = 0; j < 4; ++j) acc[i][j] = (f32x4){0.f, 0.f, 0.f, 0.f};

    const int t = threadIdx.x;
    gemm128_core(Ctx, Wto, As, Bs, D_MODEL, row0, col0, t, acc);

    const int w = t >> 6, l = t & 63, quad = l >> 4, l15 = l & 15;
    const int wm = (w & 1) * 64, wn = (w >> 1) * 64;
    #pragma unroll
    for (int mt = 0; mt < 4; ++mt) {
        #pragma unroll
        for (int nt = 0; nt < 4; ++nt) {
            int col = col0 + wn + nt * 16 + l15;
            float b = bo[col];
            #pragma unroll
            for (int reg = 0; reg < 4; ++reg) {
                int row = row0 + wm + mt * 16 + quad * 4 + reg;
                out[(size_t)row * D_MODEL + col] = acc[mt][nt][reg] + b;
            }
        }
    }
}

// ---------------------------------------------------------------------------
extern "C" void kernel_launch(void* const* d_in, const int* in_sizes, int n_in,
                              void* d_out, int out_size, void* d_ws, size_t ws_size,
                              hipStream_t stream)
{
    const float* q  = (const float*)d_in[0];
    const float* k  = (const float*)d_in[1];
    const float* v  = (const float*)d_in[2];
    const float* Wq = (const float*)d_in[3];
    const float* bq = (const float*)d_in[4];
    const float* Wk = (const float*)d_in[5];
    const float* bk = (const float*)d_in[6];
    const float* Wv = (const float*)d_in[7];
    const float* bv = (const float*)d_in[8];
    const float* Wo = (const float*)d_in[9];
    const float* bo = (const float*)d_in[10];
    float* out = (float*)d_out;

    const size_t SD = (size_t)S_LEN * D_MODEL;
    const size_t DD = (size_t)D_MODEL * D_MODEL;
    f16* base   = (f16*)d_ws;
    f16* WtBase = base;                  // Wtq|Wtk|Wtv|Wto (4*DD)
    f16* Wto    = WtBase + 3 * DD;
    f16* Qp     = base + 4 * DD;
    f16* Kp     = Qp + SD;
    f16* Vpt    = Kp + SD;               // [D][S]
    f16* qh     = Vpt + SD;              // 3SD region, reused after qkv_gemm:
    f16* kh     = qh + SD;
    f16* vh     = kh + SD;
    f16* Opart  = qh;                    //   2*SD (aliases qh,kh)
    f16* Ctx    = qh + 2 * SD;           //   1*SD (aliases vh)
    float* lsum = (float*)(base + 4 * DD + 6 * SD);  // [2][H][S]

    prep_kernel<<<3 * 1536 + 4 * 144, 256, 0, stream>>>(
        q, k, v, qh, kh, vh, Wq, Wk, Wv, Wo, WtBase);

    qkv_gemm_kernel<<<3 * 192, 256, 0, stream>>>(
        qh, kh, vh, WtBase, bq, bk, bv, Qp, Kp, Vpt);

    dim3 gAttn(S_LEN / 128, N_HEADS, SEG);   // (32, 12, 2)
    flash_attn_part_kernel<<<gAttn, 256, 0, stream>>>(Qp, Kp, Vpt, Opart, lsum);

    combine_kernel<<<1536, 256, 0, stream>>>(Opart, lsum, Ctx);

    oproj_kernel<<<192, 256, 0, stream>>>(Ctx, Wto, bo, out);
}

// Round 14
// 213.663 us; speedup vs baseline: 1.2485x; 1.0154x over previous
//
#include <hip/hip_runtime.h>
#include <hip/hip_bf16.h>

// MHA: B=1, S=4096, D=768, H=12, DK=64.
// Round 24: FULL REVERT to R16 pipeline (210.0 us best-measured; six
//   non-flash structural edits all regressed). ONE new variable: flash
//   block-ID XCD swizzle. The 32 q-tile blocks sharing one (head,seg)'s
//   512 KB K/V segment previously scattered round-robin over 8 XCD L2s ->
//   K/V re-fetched per XCD (FETCH 53 MB vs ~24 unique). New physical id
//   f = (g%8) + 8*x + 256*(g/8), g=(h,seg) group 0..23: all sharers on one
//   XCD, per-XCD K/V+Q ~3 MB (L2-resident). Bijective on 0..767; decode
//   in-kernel. Expect flash FETCH ~25-32 MB; dur 66 -> 58-64 if the
//   latency relief is real, else null -> structure floor confirmed.

constexpr int S_LEN = 4096;
constexpr int D_MODEL = 768;
constexpr int N_HEADS = 12;
constexpr int D_HEAD = 64;
constexpr int SEG = 2;
constexpr int SEG_LEN = S_LEN / SEG;   // 2048
constexpr int NITER = SEG_LEN / 64;    // 32

// Q pre-scale: (1/sqrt(64)) * log2(e)  -> scores in exp2 domain
#define QSCALE 0.180336880111120f

typedef _Float16 f16;
typedef __attribute__((ext_vector_type(8))) _Float16 f16x8;
typedef __attribute__((ext_vector_type(4))) _Float16 f16x4;
typedef __attribute__((ext_vector_type(4))) float f32x4;

// ---------------------------------------------------------------------------
// Merged prep: blocks [0, 4608) = f32->f16 convert of q,k,v (8 elem/thread);
//              blocks [4608, 5184) = W transpose+convert (144 blocks per W).
// ---------------------------------------------------------------------------
__global__ __launch_bounds__(256) void prep_kernel(
    const float* __restrict__ q, const float* __restrict__ k,
    const float* __restrict__ v, f16* __restrict__ qh,
    f16* __restrict__ kh, f16* __restrict__ vh,
    const float* __restrict__ W0, const float* __restrict__ W1,
    const float* __restrict__ W2, const float* __restrict__ W3,
    f16* __restrict__ WtBase)
{
    __shared__ float T[64][65];
    int bid = blockIdx.x;
    const int t = threadIdx.x;
    if (bid < 4608) {
        int g = bid / 1536, r = bid % 1536;
        const float* x = (g == 0) ? q : (g == 1) ? k : v;
        f16* y = (g == 0) ? qh : (g == 1) ? kh : vh;
        int i = (r * 256 + t) * 8;
        float4 a = *(const float4*)&x[i];
        float4 b = *(const float4*)&x[i + 4];
        f16x8 h = { (f16)a.x, (f16)a.y, (f16)a.z, (f16)a.w,
                    (f16)b.x, (f16)b.y, (f16)b.z, (f16)b.w };
        *(f16x8*)&y[i] = h;
        return;
    }
    bid -= 4608;
    int g = bid / 144, r = bid % 144;
    const float* W = (g == 0) ? W0 : (g == 1) ? W1 : (g == 2) ? W2 : W3;
    f16* Wt = WtBase + (size_t)g * D_MODEL * D_MODEL;
    const int r0 = (r / 12) * 64;
    const int c0 = (r % 12) * 64;
    #pragma unroll
    for (int i = 0; i < 16; ++i) {
        int e = t + 256 * i; int rr = e >> 6, cc = e & 63;
        T[rr][cc] = W[(size_t)(r0 + rr) * D_MODEL + c0 + cc];
    }
    __syncthreads();
    #pragma unroll
    for (int i = 0; i < 16; ++i) {
        int e = t + 256 * i; int rr = e >> 6, cc = e & 63;
        Wt[(size_t)(c0 + rr) * D_MODEL + r0 + cc] = (f16)T[cc][rr];
    }
}

// ---------------------------------------------------------------------------
// 128x128 GEMM core with register-prefetch pipeline (R10-proven, unchanged).
// Both operands k-contiguous (B^T form), BK=64. 4 waves 2x2; LDS stride 72.
// Staging is PURE f16 copies (R18/R19 lessons).
// ---------------------------------------------------------------------------
#define GSTR 72

__device__ __forceinline__ void gemm128_core(
    const f16* __restrict__ A, const f16* __restrict__ B,
    f16* As, f16* Bs, int K, int row0, int col0, int t, f32x4 acc[4][4])
{
    const int w = t >> 6, l = t & 63, quad = l >> 4, l15 = l & 15;
    const int wm = (w & 1) * 64, wn = (w >> 1) * 64;

    f16x8 pa[4], pb[4];
    #pragma unroll
    for (int i = 0; i < 4; ++i) {
        int idx = i * 256 + t;
        int r = idx >> 3, c = (idx & 7) * 8;
        pa[i] = *(const f16x8*)&A[(size_t)(row0 + r) * K + c];
        pb[i] = *(const f16x8*)&B[(size_t)(col0 + r) * K + c];
    }

    for (int k0 = 0; k0 < K; k0 += 64) {
        __syncthreads();
        #pragma unroll
        for (int i = 0; i < 4; ++i) {
            int idx = i * 256 + t;
            int r = idx >> 3, c = (idx & 7) * 8;
            *(f16x8*)&As[r * GSTR + c] = pa[i];
            *(f16x8*)&Bs[r * GSTR + c] = pb[i];
        }
        __syncthreads();

        int kn = k0 + 64;
        if (kn < K) {
            #pragma unroll
            for (int i = 0; i < 4; ++i) {
                int idx = i * 256 + t;
                int r = idx >> 3, c = (idx & 7) * 8;
                pa[i] = *(const f16x8*)&A[(size_t)(row0 + r) * K + kn + c];
                pb[i] = *(const f16x8*)&B[(size_t)(col0 + r) * K + kn + c];
            }
        }

        #pragma unroll
        for (int kc = 0; kc < 2; ++kc) {
            f16x8 af[4], bf[4];
            #pragma unroll
            for (int mt = 0; mt < 4; ++mt)
                af[mt] = *(f16x8*)&As[(wm + mt * 16 + l15) * GSTR + kc * 32 + quad * 8];
            #pragma unroll
            for (int nt = 0; nt < 4; ++nt)
                bf[nt] = *(f16x8*)&Bs[(wn + nt * 16 + l15) * GSTR + kc * 32 + quad * 8];
            #pragma unroll
            for (int mt = 0; mt < 4; ++mt)
                #pragma unroll
                for (int nt = 0; nt < 4; ++nt)
                    acc[mt][nt] = __builtin_amdgcn_mfma_f32_16x16x32_f16(
                        af[mt], bf[nt], acc[mt][nt], 0, 0, 0);
        }
    }
}

// ---------------------------------------------------------------------------
// Batched QKV projections (f16 inputs), 128x128 tiles, 192 blocks per GEMM:
//  g0: Qp=(qh@Wtq^T+bq)*QSCALE [SxD]; g1: Kp [SxD]; g2: Vpt=Wtv@vh^T+bv [DxS].
// ---------------------------------------------------------------------------
__global__ __launch_bounds__(256) void qkv_gemm_kernel(
    const f16* __restrict__ qh, const f16* __restrict__ kh,
    const f16* __restrict__ vh, const f16* __restrict__ WtBase,
    const float* __restrict__ bq, const float* __restrict__ bk,
    const float* __restrict__ bv,
    f16* __restrict__ Qp, f16* __restrict__ Kp, f16* __restrict__ Vpt)
{
    __shared__ f16 As[128 * GSTR];
    __shared__ f16 Bs[128 * GSTR];
    const size_t DD = (size_t)D_MODEL * D_MODEL;
    int bid = blockIdx.x;
    int g = bid / 192, r = bid % 192;

    const f16 *A, *B; const float* bias; f16* Y;
    int N; bool biasRow; float scale;
    int row0, col0;
    if (g == 0) {
        A = qh; B = WtBase; bias = bq; Y = Qp;
        N = D_MODEL; biasRow = false; scale = QSCALE;
        row0 = (r / 6) * 128; col0 = (r % 6) * 128;
    } else if (g == 1) {
        A = kh; B = WtBase + DD; bias = bk; Y = Kp;
        N = D_MODEL; biasRow = false; scale = 1.0f;
        row0 = (r / 6) * 128; col0 = (r % 6) * 128;
    } else {
        A = WtBase + 2 * DD; B = vh; bias = bv; Y = Vpt;
        N = S_LEN; biasRow = true; scale = 1.0f;
        row0 = (r / 32) * 128; col0 = (r % 32) * 128;
    }

    f32x4 acc[4][4];
    #pragma unroll
    for (int i = 0; i < 4; ++i)
        #pragma unroll
        for (int j = 0; j < 4; ++j) acc[i][j] = (f32x4){0.f, 0.f, 0.f, 0.f};

    const int t = threadIdx.x;
    gemm128_core(A, B, As, Bs, D_MODEL, row0, col0, t, acc);

    const int w = t >> 6, l = t & 63, quad = l >> 4, l15 = l & 15;
    const int wm = (w & 1) * 64, wn = (w >> 1) * 64;
    #pragma unroll
    for (int mt = 0; mt < 4; ++mt) {
        #pragma unroll
        for (int nt = 0; nt < 4; ++nt) {
            int col = col0 + wn + nt * 16 + l15;
            #pragma unroll
            for (int reg = 0; reg < 4; ++reg) {
                int row = row0 + wm + mt * 16 + quad * 4 + reg;
                float b = biasRow ? bias[row] : bias[col];
                Y[(size_t)row * N + col] = (f16)((acc[mt][nt][reg] + b) * scale);
            }
        }
    }
}

// ---------------------------------------------------------------------------
// Flash attention — R16 structure (66 us proven) + R24 XCD swizzle.
// 1D grid of 768; physical id f = (g%8) + 8*x + 256*(g/8) where g = group
// (head,seg) 0..23 and x = q-tile 0..31. Decode: gl=f&7, x=(f>>3)&31,
// gh=f>>8, g=gh*8+gl, h=g%12, seg=g/12. All 32 sharers of one (h,seg) K/V
// segment land on one XCD -> K/V+Q L2-resident (~3 MB/XCD).
// ---------------------------------------------------------------------------
#define LSTR 72

__global__ __launch_bounds__(256, 4) void flash_attn_part_kernel(
    const f16* __restrict__ Q, const f16* __restrict__ K,
    const f16* __restrict__ Vg, f16* __restrict__ Opart,
    float* __restrict__ lsum)
{
    __shared__ f16 Ks[2][64 * LSTR];
    __shared__ f16 Vt[2][64 * LSTR];

    const int t    = threadIdx.x;
    const int w    = t >> 6;
    const int l    = t & 63;
    const int quad = l >> 4;
    const int l15  = l & 15;

    // XCD-aware decode (bijective on 0..767)
    const int id   = blockIdx.x;
    const int gl   = id & 7;
    const int x    = (id >> 3) & 31;
    const int gh   = id >> 8;
    const int g    = gh * 8 + gl;        // 0..23
    const int h    = g % N_HEADS;
    const int seg  = g / N_HEADS;
    const int q0   = x * 128;

    const int c0   = h * D_HEAD;
    const size_t SD = (size_t)S_LEN * D_MODEL;

    const int sr = t >> 3;            // row 0..31  (r = i*32+sr)
    const int sc = (t & 7) * 8;       // f16 col chunk
    // sigma: kv = q*8 + h2*4 + rr -> row = h2*16 + q*4 + rr
    const int srk = ((sr & 4) << 2) | ((sr & 24) >> 1) | (sr & 3);

    f16x8 qa[2][2];
    #pragma unroll
    for (int qt = 0; qt < 2; ++qt) {
        const f16* qrow = Q + (size_t)(q0 + w * 32 + qt * 16 + l15) * D_MODEL + c0;
        qa[qt][0] = *(const f16x8*)&qrow[quad * 8];
        qa[qt][1] = *(const f16x8*)&qrow[32 + quad * 8];
    }

    f32x4 ctx[2][4];
    float lAcc[2] = {0.f, 0.f};
    #pragma unroll
    for (int qt = 0; qt < 2; ++qt)
        #pragma unroll
        for (int i = 0; i < 4; ++i) ctx[qt][i] = (f32x4){0.f, 0.f, 0.f, 0.f};

    const int kt0 = seg * SEG_LEN;

    f16x8 kreg[2], vreg[2];
    #pragma unroll
    for (int i = 0; i < 2; ++i) {
        int r = i * 32 + sr;
        kreg[i] = *(const f16x8*)&K[(size_t)(kt0 + r) * D_MODEL + c0 + sc];
        vreg[i] = *(const f16x8*)&Vg[(size_t)(c0 + r) * S_LEN + kt0 + sc];
    }
    #pragma unroll
    for (int i = 0; i < 2; ++i) {
        int r = i * 32 + sr;
        *(f16x8*)&Ks[0][(i * 32 + srk) * LSTR + sc] = kreg[i];
        *(f16x8*)&Vt[0][r * LSTR + sc] = vreg[i];
    }
    __syncthreads();
    #pragma unroll
    for (int i = 0; i < 2; ++i) {
        int r = i * 32 + sr;
        kreg[i] = *(const f16x8*)&K[(size_t)(kt0 + 64 + r) * D_MODEL + c0 + sc];
        vreg[i] = *(const f16x8*)&Vg[(size_t)(c0 + r) * S_LEN + kt0 + 64 + sc];
    }

    for (int it = 0; it < NITER; ++it) {
        const int buf = it & 1;
        const f16* ks = Ks[buf];
        const f16* vt = Vt[buf];

        f16x8 pf[2][2];       // [qt][kslot]
        #pragma unroll
        for (int s = 0; s < 4; ++s) {
            const int kslot = s >> 1, half = s & 1;
            const f16* kr = &ks[(kslot * 32 + half * 16 + l15) * LSTR];
            f16x8 kb0 = *(const f16x8*)&kr[quad * 8];
            f16x8 kb1 = *(const f16x8*)&kr[32 + quad * 8];
            #pragma unroll
            for (int qt = 0; qt < 2; ++qt) {
                f32x4 z = (f32x4){0.f, 0.f, 0.f, 0.f};
                z = __builtin_amdgcn_mfma_f32_16x16x32_f16(kb0, qa[qt][0], z, 0, 0, 0);
                z = __builtin_amdgcn_mfma_f32_16x16x32_f16(kb1, qa[qt][1], z, 0, 0, 0);
                float p0 = __builtin_amdgcn_exp2f(z[0]);
                float p1 = __builtin_amdgcn_exp2f(z[1]);
                float p2 = __builtin_amdgcn_exp2f(z[2]);
                float p3 = __builtin_amdgcn_exp2f(z[3]);
                lAcc[qt] += (p0 + p1) + (p2 + p3);
                pf[qt][kslot][half * 4 + 0] = (f16)p0;
                pf[qt][kslot][half * 4 + 1] = (f16)p1;
                pf[qt][kslot][half * 4 + 2] = (f16)p2;
                pf[qt][kslot][half * 4 + 3] = (f16)p3;
            }
        }

        #pragma unroll
        for (int mt = 0; mt < 4; ++mt) {
            #pragma unroll
            for (int ks2 = 0; ks2 < 2; ++ks2) {
                f16x8 va = *(const f16x8*)&vt[(mt * 16 + l15) * LSTR + ks2 * 32 + quad * 8];
                #pragma unroll
                for (int qt = 0; qt < 2; ++qt)
                    ctx[qt][mt] = __builtin_amdgcn_mfma_f32_16x16x32_f16(
                        va, pf[qt][ks2], ctx[qt][mt], 0, 0, 0);
            }
        }

        if (it + 1 < NITER) {
            #pragma unroll
            for (int i = 0; i < 2; ++i) {
                int r = i * 32 + sr;
                *(f16x8*)&Ks[1 - buf][(i * 32 + srk) * LSTR + sc] = kreg[i];
                *(f16x8*)&Vt[1 - buf][r * LSTR + sc] = vreg[i];
            }
        }
        __syncthreads();

        if (it + 2 < NITER) {
            int ktn = kt0 + (it + 2) * 64;
            #pragma unroll
            for (int i = 0; i < 2; ++i) {
                int r = i * 32 + sr;
                kreg[i] = *(const f16x8*)&K[(size_t)(ktn + r) * D_MODEL + c0 + sc];
                vreg[i] = *(const f16x8*)&Vg[(size_t)(c0 + r) * S_LEN + ktn + sc];
            }
        }
    }

    #pragma unroll
    for (int qt = 0; qt < 2; ++qt) {
        int qrow = q0 + w * 32 + qt * 16 + l15;
        #pragma unroll
        for (int mt = 0; mt < 4; ++mt) {
            f16x4 ov = { (f16)ctx[qt][mt][0], (f16)ctx[qt][mt][1],
                         (f16)ctx[qt][mt][2], (f16)ctx[qt][mt][3] };
            *(f16x4*)&Opart[(size_t)seg * SD + (size_t)qrow * D_MODEL
                            + c0 + mt * 16 + quad * 4] = ov;
        }
        float s = lAcc[qt];
        s += __shfl_xor(s, 16);
        s += __shfl_xor(s, 32);
        if (quad == 0)
            lsum[((size_t)seg * N_HEADS + h) * S_LEN + qrow] = s;
    }
}

// ---------------------------------------------------------------------------
// Combine 2 segments: Ctx = (O0 + O1) / (l0 + l1).  1536 blocks.
// ---------------------------------------------------------------------------
__global__ __launch_bounds__(256) void combine_kernel(
    const f16* __restrict__ Opart, const float* __restrict__ lsum,
    f16* __restrict__ Ctx)
{
    const size_t SD = (size_t)S_LEN * D_MODEL;
    int tid = blockIdx.x * 256 + threadIdx.x;
    int idx = tid * 8;
    int row = idx / D_MODEL;
    int c   = idx % D_MODEL;
    int h   = c >> 6;
    float l0 = lsum[(size_t)h * S_LEN + row];
    float l1 = lsum[((size_t)N_HEADS + h) * S_LEN + row];
    float inv = 1.0f / (l0 + l1);
    f16x8 o0 = *(const f16x8*)&Opart[(size_t)row * D_MODEL + c];
    f16x8 o1 = *(const f16x8*)&Opart[SD + (size_t)row * D_MODEL + c];
    f16x8 r;
    #pragma unroll
    for (int j = 0; j < 8; ++j)
        r[j] = (f16)(((float)o0[j] + (float)o1[j]) * inv);
    *(f16x8*)&Ctx[(size_t)row * D_MODEL + c] = r;
}

// ---------------------------------------------------------------------------
// O-projection: out_f32 = Ctx @ Wto^T + bo.  128x128 tiles, 192 blocks.
// ---------------------------------------------------------------------------
__global__ __launch_bounds__(256) void oproj_kernel(
    const f16* __restrict__ Ctx, const f16* __restrict__ Wto,
    const float* __restrict__ bo, float* __restrict__ out)
{
    __shared__ f16 As[128 * GSTR];
    __shared__ f16 Bs[128 * GSTR];
    int bid = blockIdx.x;
    int row0 = (bid / 6) * 128, col0 = (bid % 6) * 128;

    f32x4 acc[4][4];
    #pragma unroll
    for (int i = 0; i < 4; ++i)
        #pragma unroll
        for (int j = 0; j < 4; ++j) acc[i][j] = (f32x4){0.f, 0.f, 0.f, 0.f};

    const int t = threadIdx.x;
    gemm128_core(Ctx, Wto, As, Bs, D_MODEL, row0, col0, t, acc);

    const int w = t >> 6, l = t & 63, quad = l >> 4, l15 = l & 15;
    const int wm = (w & 1) * 64, wn = (w >> 1) * 64;
    #pragma unroll
    for (int mt = 0; mt < 4; ++mt) {
        #pragma unroll
        for (int nt = 0; nt < 4; ++nt) {
            int col = col0 + wn + nt * 16 + l15;
            float b = bo[col];
            #pragma unroll
            for (int reg = 0; reg < 4; ++reg) {
                int row = row0 + wm + mt * 16 + quad * 4 + reg;
                out[(size_t)row * D_MODEL + col] = acc[mt][nt][reg] + b;
            }
        }
    }
}

// ---------------------------------------------------------------------------
extern "C" void kernel_launch(void* const* d_in, const int* in_sizes, int n_in,
                              void* d_out, int out_size, void* d_ws, size_t ws_size,
                              hipStream_t stream)
{
    const float* q  = (const float*)d_in[0];
    const float* k  = (const float*)d_in[1];
    const float* v  = (const float*)d_in[2];
    const float* Wq = (const float*)d_in[3];
    const float* bq = (const float*)d_in[4];
    const float* Wk = (const float*)d_in[5];
    const float* bk = (const float*)d_in[6];
    const float* Wv = (const float*)d_in[7];
    const float* bv = (const float*)d_in[8];
    const float* Wo = (const float*)d_in[9];
    const float* bo = (const float*)d_in[10];
    float* out = (float*)d_out;

    const size_t SD = (size_t)S_LEN * D_MODEL;
    const size_t DD = (size_t)D_MODEL * D_MODEL;
    f16* base   = (f16*)d_ws;
    f16* WtBase = base;                  // Wtq|Wtk|Wtv|Wto (4*DD)
    f16* Wto    = WtBase + 3 * DD;
    f16* Qp     = base + 4 * DD;
    f16* Kp     = Qp + SD;
    f16* Vpt    = Kp + SD;               // [D][S]
    f16* qh     = Vpt + SD;              // 3SD region, reused after qkv_gemm:
    f16* kh     = qh + SD;
    f16* vh     = kh + SD;
    f16* Opart  = qh;                    //   2*SD (aliases qh,kh)
    f16* Ctx    = qh + 2 * SD;           //   1*SD (aliases vh)
    float* lsum = (float*)(base + 4 * DD + 6 * SD);  // [2][H][S]

    prep_kernel<<<3 * 1536 + 4 * 144, 256, 0, stream>>>(
        q, k, v, qh, kh, vh, Wq, Wk, Wv, Wo, WtBase);

    qkv_gemm_kernel<<<3 * 192, 256, 0, stream>>>(
        qh, kh, vh, WtBase, bq, bk, bv, Qp, Kp, Vpt);

    flash_attn_part_kernel<<<768, 256, 0, stream>>>(Qp, Kp, Vpt, Opart, lsum);

    combine_kernel<<<1536, 256, 0, stream>>>(Opart, lsum, Ctx);

    oproj_kernel<<<192, 256, 0, stream>>>(Ctx, Wto, bo, out);
}